// Round 3
// baseline (268.885 us; speedup 1.0000x reference)
//
#include <hip/hip_runtime.h>

#define NC 50000
#define NG 3000
#define D  64

#define NB_CG 750    // gene bins of 4  (shift 2)
#define NB_GC 782    // cell bins of 64 (shift 6), 782*64 = 50048
#define PBITS 18
#define TILE  4096
#define NPREP 128
#define CAP   4608   // fixed per-bin capacity (mean ~4000, +9.6 sigma for uniform dst)
#define GG_CAP 128   // per-gene gg capacity (mean ~33)
#define OVF_CAP 262144

__device__ inline unsigned short f2bf(float x) {
    unsigned u = __float_as_uint(x);
    unsigned r = u + 0x7FFFu + ((u >> 16) & 1u);
    return (unsigned short)(r >> 16);
}

// unpack a uint4 of 8 bf16 and accumulate (features are pre-weighted)
__device__ __forceinline__ void acc8(const uint4& q, float f[8]) {
    f[0] += __uint_as_float(q.x << 16); f[1] += __uint_as_float(q.x & 0xFFFF0000u);
    f[2] += __uint_as_float(q.y << 16); f[3] += __uint_as_float(q.y & 0xFFFF0000u);
    f[4] += __uint_as_float(q.z << 16); f[5] += __uint_as_float(q.z & 0xFFFF0000u);
    f[6] += __uint_as_float(q.w << 16); f[7] += __uint_as_float(q.w & 0xFFFF0000u);
}

// fp32 fallback row loader: lane l8 holds 8 elements of row s.
__device__ inline void row8f(const float* feat, int s, int l8, float f[8]) {
    const float4* row = (const float4*)(feat + (size_t)s * D);
    const float4 a = row[l8];
    const float4 b = row[l8 + 8];
    f[0] = a.x; f[1] = a.y; f[2] = a.z; f[3] = a.w;
    f[4] = b.x; f[5] = b.y; f[6] = b.z; f[7] = b.w;
}

// ======================= single-pass partition: tiles -> fixed-cap bins =======================
// Per tile: LDS hist -> LDS scan (+global reservation fused in) -> LDS-staged bin-sorted
// placement (toff doubles as cursor) -> coalesced run flush.
// LDS ~25.8 KB -> 6 blocks/CU (was 44.5 KB / 3 blocks): latency-bound phases overlap.

__global__ __launch_bounds__(256) void partition_kernel(
    const int* __restrict__ src_cg, const int* __restrict__ dst_cg, int e_cg, int nt_cg,
    const int* __restrict__ src_gc, const int* __restrict__ dst_gc, int e_gc, int nt_gc,
    const int* __restrict__ src_gg, const int* __restrict__ dst_gg, int e_gg,
    int* __restrict__ cur_cg, int* __restrict__ cur_gc, int* __restrict__ cnt_gg,
    unsigned* __restrict__ bkt_cg, unsigned* __restrict__ bkt_gc, int* __restrict__ bkt_gg,
    int* __restrict__ ovf_cnt, uint2* __restrict__ ovf,
    const float* __restrict__ cj_cell, const float* __restrict__ mask_exp,
    const float* __restrict__ cj_gene, const float* __restrict__ mask_rev,
    const float* __restrict__ cjj_gene, const float* __restrict__ mask_gg,
    float* __restrict__ w_cell, float* __restrict__ w_rev, float* __restrict__ w_gg,
    const float* __restrict__ c_feat, const float* __restrict__ g_feat,
    unsigned short* __restrict__ wc16, unsigned short* __restrict__ wg16,
    unsigned short* __restrict__ wgg16, int do_cvt)
{
    const int tid = threadIdx.x;
    const int NT2 = nt_cg + nt_gc;

    if (blockIdx.x >= NT2 + 64) {              // ---- prep blocks ----
        const int pb = blockIdx.x - NT2 - 64;
        const long long stride = (long long)NPREP * 256;
        for (long long i = (long long)pb * 256 + tid; i < NC; i += stride)
            w_cell[i] = cj_cell[i] * mask_exp[i];
        for (long long i = (long long)pb * 256 + tid; i < NG; i += stride) {
            w_rev[i] = cj_gene[i] * mask_rev[i];
            w_gg[i]  = cjj_gene[i] * mask_gg[i];
        }
        if (do_cvt) {
            const long long total8 = (long long)(NC + NG) * D / 8;
            for (long long t = (long long)pb * 256 + tid; t < total8; t += stride) {
                const long long base = t * 8;
                if (base < (long long)NC * D) {
                    const int s = (int)(base >> 6);
                    const float w = cj_cell[s] * mask_exp[s];
                    const float4 a = ((const float4*)(c_feat + base))[0];
                    const float4 b = ((const float4*)(c_feat + base))[1];
                    unsigned short* dp = wc16 + base;
                    ((ushort4*)dp)[0] = make_ushort4(f2bf(w*a.x), f2bf(w*a.y), f2bf(w*a.z), f2bf(w*a.w));
                    ((ushort4*)dp)[1] = make_ushort4(f2bf(w*b.x), f2bf(w*b.y), f2bf(w*b.z), f2bf(w*b.w));
                } else {
                    const long long gb = base - (long long)NC * D;
                    const int s = (int)(gb >> 6);
                    const float wr = cj_gene[s] * mask_rev[s];
                    const float wg = cjj_gene[s] * mask_gg[s];
                    const float4 a = ((const float4*)(g_feat + gb))[0];
                    const float4 b = ((const float4*)(g_feat + gb))[1];
                    ((ushort4*)(wg16 + gb))[0]  = make_ushort4(f2bf(wr*a.x), f2bf(wr*a.y), f2bf(wr*a.z), f2bf(wr*a.w));
                    ((ushort4*)(wg16 + gb))[1]  = make_ushort4(f2bf(wr*b.x), f2bf(wr*b.y), f2bf(wr*b.z), f2bf(wr*b.w));
                    ((ushort4*)(wgg16 + gb))[0] = make_ushort4(f2bf(wg*a.x), f2bf(wg*a.y), f2bf(wg*a.z), f2bf(wg*a.w));
                    ((ushort4*)(wgg16 + gb))[1] = make_ushort4(f2bf(wg*b.x), f2bf(wg*b.y), f2bf(wg*b.z), f2bf(wg*b.w));
                }
            }
            if (pb == 0) {                     // zero dummy rows (tail lanes read these)
                for (int i = tid; i < D; i += 256) {
                    wc16[(size_t)NC * D + i] = 0;
                    wg16[(size_t)NG * D + i] = 0;
                    wgg16[(size_t)NG * D + i] = 0;
                }
            }
        }
        return;
    }

    if (blockIdx.x >= NT2) {                   // ---- gg direct partition (64 blocks) ----
        for (long long e = (long long)(blockIdx.x - NT2) * 256 + tid; e < e_gg;
             e += (long long)64 * 256) {
            const int dd = dst_gg[e];
            const int ss = src_gg[e];
            if ((unsigned)dd >= (unsigned)NG || (unsigned)ss >= (unsigned)NG) continue;
            const int pos = atomicAdd(&cnt_gg[dd], 1);
            if (pos < GG_CAP) bkt_gg[dd * GG_CAP + pos] = ss;
            else {
                const int op = atomicAdd(ovf_cnt, 1);
                if (op >= 0 && op < OVF_CAP)
                    ovf[op] = make_uint2((2u << 30) | (unsigned)ss, (unsigned)dd);
            }
        }
        return;
    }

    // ---- tiled partition for cg / gc ----
    const int* src; const int* dst; int ne; int* cur; unsigned* bkt;
    int shift, nbins, t; unsigned rel;
    if (blockIdx.x < nt_cg) { src = src_cg; dst = dst_cg; ne = e_cg; cur = cur_cg; bkt = bkt_cg; shift = 2; nbins = NB_CG; t = blockIdx.x;         rel = 0u; }
    else                    { src = src_gc; dst = dst_gc; ne = e_gc; cur = cur_gc; bkt = bkt_gc; shift = 6; nbins = NB_GC; t = blockIdx.x - nt_cg; rel = 1u; }
    const long long tb = (long long)t * TILE;
    if (tb >= ne) return;
    const int n = (int)((ne - tb) < TILE ? (ne - tb) : TILE);

    __shared__ int th[784];
    __shared__ int toff[784];                  // scan result, then placement cursor
    __shared__ int gs[784];                    // reserved global start within each bin
    __shared__ unsigned staged[TILE];
    const unsigned PMASK = (1u << PBITS) - 1u;
    const unsigned DMASK = (1u << shift) - 1u;

    for (int i = tid; i < nbins; i += 256) th[i] = 0;
    __syncthreads();
    #pragma unroll 4
    for (int k = 0; k < TILE / 256; ++k) {     // histogram
        int i = k * 256 + tid;
        if (i < n) {
            unsigned b = ((unsigned)dst[tb + i]) >> shift;
            if (b < (unsigned)nbins) atomicAdd(&th[b], 1);
        }
    }
    __syncthreads();
    if (tid < 64) {                            // exclusive scan th -> toff, fused reservation
        int carry = 0;
        for (int c = 0; c < nbins; c += 64) {
            int idx = c + tid;
            int v = (idx < nbins) ? th[idx] : 0;
            int incl = v;
            #pragma unroll
            for (int d = 1; d < 64; d <<= 1) {
                int x = __shfl_up(incl, d);
                if (tid >= d) incl += x;
            }
            if (idx < nbins) {
                toff[idx] = incl - v + carry;
                gs[idx] = v ? atomicAdd(&cur[idx], v) : 0;
            }
            carry += __shfl(incl, 63);
        }
    }
    __syncthreads();
    #pragma unroll 4
    for (int k = 0; k < TILE / 256; ++k) {     // bin-sorted placement into LDS (toff = cursor)
        int i = k * 256 + tid;
        if (i < n) {
            unsigned d = (unsigned)dst[tb + i];
            unsigned s = (unsigned)src[tb + i];
            unsigned b = d >> shift;
            if (b < (unsigned)nbins) {
                int p = atomicAdd(&toff[b], 1);
                if (p >= 0 && p < TILE)
                    staged[p] = (b << PBITS) | (s << shift) | (d & DMASK);
            }
        }
    }
    __syncthreads();
    for (int i = tid; i < n; i += 256) {       // flush contiguous runs to fixed-cap bins
        const unsigned v = staged[i];
        const unsigned b = v >> PBITS;
        if (b < (unsigned)nbins) {
            const int orig = toff[b] - th[b];  // post-placement toff = orig + th
            const int local = gs[b] + (i - orig);
            if (local >= 0 && local < CAP) {
                bkt[(size_t)b * CAP + local] = v & PMASK;
            } else {                           // rare overflow -> spill list
                const unsigned s = (v >> shift) & 0xFFFFu;
                const unsigned dd = (b << shift) | (v & DMASK);
                const int op = atomicAdd(ovf_cnt, 1);
                if (op >= 0 && op < OVF_CAP)
                    ovf[op] = make_uint2((rel << 30) | s, dd);
            }
        }
    }
}

// ======================= fused gather (cg + gg fold | gc), fixed-cap bins =======================
// BF16 path: features are PRE-WEIGHTED bf16 rows; tail lanes read a zero dummy row.
// Overflow edges (normally none) are folded in by the owning block before the store.

template <bool BF16>
__global__ __launch_bounds__(256, 6) void gather3_kernel(
    const unsigned* __restrict__ bkt_cg, const int* __restrict__ cur_cg,
    const unsigned* __restrict__ bkt_gc, const int* __restrict__ cur_gc,
    const void* __restrict__ fc, const void* __restrict__ fg, const void* __restrict__ fgg,
    const float* __restrict__ craw, const float* __restrict__ graw,
    const float* __restrict__ w_cell, const float* __restrict__ w_rev, const float* __restrict__ w_gg,
    const float* __restrict__ ci_gene, const float* __restrict__ cii_gene, const float* __restrict__ ci_cell,
    const int* __restrict__ cnt_gg, const int* __restrict__ bkt_gg,
    const int* __restrict__ ovf_cnt, const uint2* __restrict__ ovf,
    float* __restrict__ g_out, float* __restrict__ c_out)
{
    __shared__ unsigned short sorted[CAP];     // source ids only (16-bit)
    __shared__ int lh[64];
    __shared__ int loff[64];
    __shared__ int lcur[64];

    const bool is_cg = (blockIdx.x < NB_CG);
    const int bin = is_cg ? blockIdx.x : blockIdx.x - NB_CG;
    int n = (is_cg ? cur_cg : cur_gc)[bin];
    n = n > CAP ? CAP : n;
    const long long base = (long long)bin * CAP;
    const unsigned* bkt = is_cg ? bkt_cg : bkt_gc;
    const void* feat = is_cg ? fc : fg;
    const float* wsrc = is_cg ? w_cell : w_rev;
    const int shift = is_cg ? 2 : 6;
    const int DIVv = is_cg ? 4 : 64;
    const int KPC  = is_cg ? 16 : 1;           // sort keys per output row
    const int DUM  = is_cg ? NC : NG;          // zero dummy row index
    const int tid  = threadIdx.x;
    const int lane = tid & 63;
    const int wid  = tid >> 6;
    const int grp8 = lane >> 3;                // 8 groups of 8 lanes -> 8 edges in flight
    const int l8   = lane & 7;

    // ---- 64-key counting sort into LDS (by cell-in-bin, then src-high for locality) ----
    for (int i = tid; i < 64; i += 256) { lh[i] = 0; lcur[i] = 0; }
    __syncthreads();
    for (int i = tid; i < n; i += 256) {
        const unsigned v = bkt[base + i];
        const int k = is_cg ? (int)(((v & 3u) << 4) | (((v >> 2) & 0xFFFFu) >> 12))
                            : (int)(v & 63u);
        atomicAdd(&lh[k], 1);
    }
    __syncthreads();
    if (tid < 64) {
        int v = lh[tid];
        int incl = v;
        #pragma unroll
        for (int d = 1; d < 64; d <<= 1) {
            int t = __shfl_up(incl, d);
            if (tid >= d) incl += t;
        }
        loff[tid] = incl - v;
    }
    __syncthreads();
    for (int i = tid; i < n; i += 256) {
        const unsigned v = bkt[base + i];
        const int k = is_cg ? (int)(((v & 3u) << 4) | (((v >> 2) & 0xFFFFu) >> 12))
                            : (int)(v & 63u);
        const int p = loff[k] + atomicAdd(&lcur[k], 1);
        if (p >= 0 && p < CAP) sorted[p] = (unsigned short)((v >> shift) & 0xFFFFu);
    }
    __syncthreads();

    int novf = *ovf_cnt;
    novf = novf < 0 ? 0 : (novf > OVF_CAP ? OVF_CAP : novf);

    for (int cell = wid; cell < DIVv; cell += 4) {
        const int r = (bin << shift) + cell;
        if (r >= (is_cg ? NG : NC)) continue;

        float fA[8] = {0.f, 0.f, 0.f, 0.f, 0.f, 0.f, 0.f, 0.f};
        {
            const int k0 = cell * KPC, k1 = k0 + KPC - 1;
            const int lo = loff[k0], hi = loff[k1] + lh[k1];
            if (BF16) {
                const uint4* fp = (const uint4*)feat;
                for (int jj = lo; jj < hi; jj += 32) {   // 4 rows in flight per group
                    const int b0 = jj + grp8;
                    const int s0 = (b0      < hi) ? (int)sorted[b0]      : DUM;
                    const int s1 = (b0 + 8  < hi) ? (int)sorted[b0 + 8]  : DUM;
                    const int s2 = (b0 + 16 < hi) ? (int)sorted[b0 + 16] : DUM;
                    const int s3 = (b0 + 24 < hi) ? (int)sorted[b0 + 24] : DUM;
                    const uint4 q0 = fp[(size_t)s0 * 8 + l8];
                    const uint4 q1 = fp[(size_t)s1 * 8 + l8];
                    const uint4 q2 = fp[(size_t)s2 * 8 + l8];
                    const uint4 q3 = fp[(size_t)s3 * 8 + l8];
                    acc8(q0, fA); acc8(q1, fA); acc8(q2, fA); acc8(q3, fA);
                }
            } else {
                for (int jj = lo; jj < hi; jj += 8) {
                    const int j = jj + grp8;
                    const bool valid = (j < hi);
                    const int s = valid ? (int)sorted[j] : 0;
                    const float w = valid ? wsrc[s] : 0.0f;
                    float f[8]; row8f((const float*)feat, s, l8, f);
                    #pragma unroll
                    for (int q = 0; q < 8; ++q) fA[q] += w * f[q];
                }
            }
        }

        float fB[8] = {0.f, 0.f, 0.f, 0.f, 0.f, 0.f, 0.f, 0.f};
        if (is_cg) {
            int ngg = cnt_gg[r];
            ngg = ngg > GG_CAP ? GG_CAP : ngg;
            const int* bg = bkt_gg + (size_t)r * GG_CAP;
            if (BF16) {
                const uint4* fp = (const uint4*)fgg;
                for (int jj = 0; jj < ngg; jj += 16) {   // 2 rows in flight
                    const int j0 = jj + grp8;
                    const int j1 = jj + 8 + grp8;
                    const int s0 = (j0 < ngg) ? bg[j0] : NG;
                    const int s1 = (j1 < ngg) ? bg[j1] : NG;
                    const uint4 q0 = fp[(size_t)s0 * 8 + l8];
                    const uint4 q1 = fp[(size_t)s1 * 8 + l8];
                    acc8(q0, fB); acc8(q1, fB);
                }
            } else {
                for (int jj = 0; jj < ngg; jj += 8) {
                    const int j = jj + grp8;
                    const bool valid = (j < ngg);
                    const int s = valid ? bg[j] : 0;
                    const float w = valid ? w_gg[s] : 0.0f;
                    float f[8]; row8f(graw, s, l8, f);
                    #pragma unroll
                    for (int q = 0; q < 8; ++q) fB[q] += w * f[q];
                }
            }
        }

        #pragma unroll
        for (int q = 0; q < 8; ++q) {
            #pragma unroll
            for (int off = 8; off < 64; off <<= 1) fA[q] += __shfl_xor(fA[q], off);
        }
        if (is_cg) {
            #pragma unroll
            for (int q = 0; q < 8; ++q) {
                #pragma unroll
                for (int off = 8; off < 64; off <<= 1) fB[q] += __shfl_xor(fB[q], off);
            }
        }

        if (grp8 == 0) {
            float o[8];
            float* outp;
            if (is_cg) {
                const float sa = 0.5f * ci_gene[r];
                const float sb = 0.5f * cii_gene[r];
                outp = g_out + (size_t)r * D;
                #pragma unroll
                for (int q = 0; q < 8; ++q) o[q] = sa * fA[q] + sb * fB[q];
            } else {
                const float sc = ci_cell[r];
                outp = c_out + (size_t)r * D;
                #pragma unroll
                for (int q = 0; q < 8; ++q) o[q] = sc * fA[q];
            }

            if (novf > 0) {                    // fold rare overflow edges for this row
                for (int e = 0; e < novf; ++e) {
                    const uint2 vv = ovf[e];
                    const int d = (int)vv.y;
                    if (d != r) continue;
                    const unsigned relv = vv.x >> 30;
                    const int s = (int)(vv.x & 0x3FFFFFFFu);
                    const float* fr = nullptr; float w = 0.f;
                    if (is_cg) {
                        if (relv == 0u && s < NC)      { fr = craw + (size_t)s * D; w = 0.5f * ci_gene[r] * w_cell[s]; }
                        else if (relv == 2u && s < NG) { fr = graw + (size_t)s * D; w = 0.5f * cii_gene[r] * w_gg[s]; }
                    } else {
                        if (relv == 1u && s < NG)      { fr = graw + (size_t)s * D; w = ci_cell[r] * w_rev[s]; }
                    }
                    if (fr) {
                        #pragma unroll
                        for (int q = 0; q < 8; ++q) {
                            const int elem = BF16 ? (8 * l8 + q)
                                                  : (q < 4 ? 4 * l8 + q : 32 + 4 * l8 + (q - 4));
                            o[q] += w * fr[elem];
                        }
                    }
                }
            }

            if (BF16) {
                *(float4*)(outp + 8 * l8)     = make_float4(o[0], o[1], o[2], o[3]);
                *(float4*)(outp + 8 * l8 + 4) = make_float4(o[4], o[5], o[6], o[7]);
            } else {
                *(float4*)(outp + 4 * l8)      = make_float4(o[0], o[1], o[2], o[3]);
                *(float4*)(outp + 32 + 4 * l8) = make_float4(o[4], o[5], o[6], o[7]);
            }
        }
    }
}

// ======================= fallback (atomic scatter) =======================

__global__ __launch_bounds__(256) void edge_scatter_kernel(
    const float* __restrict__ feat, const float* __restrict__ cj,
    const float* __restrict__ mask, const float* __restrict__ ci,
    const int* __restrict__ src, const int* __restrict__ dst,
    float* __restrict__ out, int nedges, float alpha)
{
    const int lane16 = threadIdx.x & 15;
    const int eloc   = threadIdx.x >> 4;
    const long long e = (long long)blockIdx.x * 16 + eloc;
    if (e >= nedges) return;
    const int s = src[e];
    const int t = dst[e];
    const float w = cj[s] * mask[s] * ci[t] * alpha;
    const float4 v = *(const float4*)(feat + (size_t)s * D + lane16 * 4);
    float* o = out + (size_t)t * D + lane16 * 4;
#if defined(__HIP_DEVICE_COMPILE__)
    unsafeAtomicAdd(o + 0, w * v.x);
    unsafeAtomicAdd(o + 1, w * v.y);
    unsafeAtomicAdd(o + 2, w * v.z);
    unsafeAtomicAdd(o + 3, w * v.w);
#endif
}

// ======================= launch =======================

extern "C" void kernel_launch(void* const* d_in, const int* in_sizes, int n_in,
                              void* d_out, int out_size, void* d_ws, size_t ws_size,
                              hipStream_t stream)
{
    const float* c_feat   = (const float*)d_in[0];
    const float* g_feat   = (const float*)d_in[1];
    const float* cj_cell  = (const float*)d_in[2];
    const float* ci_cell  = (const float*)d_in[3];
    const float* cj_gene  = (const float*)d_in[4];
    const float* ci_gene  = (const float*)d_in[5];
    const float* cjj_gene = (const float*)d_in[6];
    const float* cii_gene = (const float*)d_in[7];
    const float* mask_exp = (const float*)d_in[8];
    const float* mask_rev = (const float*)d_in[9];
    const float* mask_gg  = (const float*)d_in[10];
    const int*   src_cg   = (const int*)d_in[11];
    const int*   dst_cg   = (const int*)d_in[12];
    const int*   src_gc   = (const int*)d_in[13];
    const int*   dst_gc   = (const int*)d_in[14];
    const int*   src_gg   = (const int*)d_in[15];
    const int*   dst_gg   = (const int*)d_in[16];

    const int e_cg = in_sizes[11];
    const int e_gc = in_sizes[13];
    const int e_gg = in_sizes[15];

    float* c_out = (float*)d_out;                   // [NC, D]
    float* g_out = (float*)d_out + (size_t)NC * D;  // [NG, D]

    const int nt_cg = (e_cg + TILE - 1) / TILE;
    const int nt_gc = (e_gc + TILE - 1) / TILE;

    // ---- workspace layout (int units) ----
    int* ws = (int*)d_ws;
    size_t p = 0;
    int* cur_cg  = ws + p; p += NB_CG;       // memset region start
    int* cur_gc  = ws + p; p += NB_GC;
    int* cnt_gg  = ws + p; p += NG;
    int* ovf_cnt = ws + p; p += 1;           // memset region end
    const size_t zcount = p;
    float* w_cell = (float*)(ws + p); p += NC;
    float* w_rev  = (float*)(ws + p); p += NG;
    float* w_gg   = (float*)(ws + p); p += NG;
    unsigned* bkt_cg = (unsigned*)(ws + p); p += (size_t)NB_CG * CAP;
    unsigned* bkt_gc = (unsigned*)(ws + p); p += (size_t)NB_GC * CAP;
    int* bkt_gg = ws + p; p += (size_t)NG * GG_CAP;
    p = (p + 1) & ~(size_t)1;                // 8B align for uint2
    uint2* ovf = (uint2*)(ws + p); p += (size_t)OVF_CAP * 2;
    const size_t need_base = p * sizeof(int);
    p = (p + 3) & ~(size_t)3;                // 16B align for uint4 reads
    unsigned short* wc16  = (unsigned short*)(ws + p); p += (size_t)(NC + 1) * D / 2;
    unsigned short* wg16  = (unsigned short*)(ws + p); p += (size_t)(NG + 1) * D / 2;
    unsigned short* wgg16 = (unsigned short*)(ws + p); p += (size_t)(NG + 1) * D / 2;
    const size_t need_full = p * sizeof(int);

    // fallback if workspace too small or sizes pathological for fixed-cap bins
    if (need_base > ws_size || e_cg > 3200000 || e_gc > 3200000 || e_gg > 200000) {
        hipMemsetAsync(d_out, 0, (size_t)out_size * sizeof(float), stream);
        edge_scatter_kernel<<<(e_cg + 15) / 16, 256, 0, stream>>>(
            c_feat, cj_cell, mask_exp, ci_gene, src_cg, dst_cg, g_out, e_cg, 0.5f);
        edge_scatter_kernel<<<(e_gc + 15) / 16, 256, 0, stream>>>(
            g_feat, cj_gene, mask_rev, ci_cell, src_gc, dst_gc, c_out, e_gc, 1.0f);
        edge_scatter_kernel<<<(e_gg + 15) / 16, 256, 0, stream>>>(
            g_feat, cjj_gene, mask_gg, cii_gene, src_gg, dst_gg, g_out, e_gg, 0.5f);
        return;
    }
    const int use_bf16 = (need_full <= ws_size) ? 1 : 0;

    hipMemsetAsync(ws, 0, zcount * sizeof(int), stream);

    partition_kernel<<<nt_cg + nt_gc + 64 + NPREP, 256, 0, stream>>>(
        src_cg, dst_cg, e_cg, nt_cg,
        src_gc, dst_gc, e_gc, nt_gc,
        src_gg, dst_gg, e_gg,
        cur_cg, cur_gc, cnt_gg,
        bkt_cg, bkt_gc, bkt_gg,
        ovf_cnt, ovf,
        cj_cell, mask_exp, cj_gene, mask_rev, cjj_gene, mask_gg,
        w_cell, w_rev, w_gg, c_feat, g_feat, wc16, wg16, wgg16, use_bf16);

    if (use_bf16) {
        gather3_kernel<true><<<NB_CG + NB_GC, 256, 0, stream>>>(
            bkt_cg, cur_cg, bkt_gc, cur_gc,
            (const void*)wc16, (const void*)wg16, (const void*)wgg16,
            c_feat, g_feat,
            w_cell, w_rev, w_gg, ci_gene, cii_gene, ci_cell,
            cnt_gg, bkt_gg, ovf_cnt, ovf, g_out, c_out);
    } else {
        gather3_kernel<false><<<NB_CG + NB_GC, 256, 0, stream>>>(
            bkt_cg, cur_cg, bkt_gc, cur_gc,
            (const void*)c_feat, (const void*)g_feat, (const void*)g_feat,
            c_feat, g_feat,
            w_cell, w_rev, w_gg, ci_gene, cii_gene, ci_cell,
            cnt_gg, bkt_gg, ovf_cnt, ovf, g_out, c_out);
    }
}

// Round 5
// 252.219 us; speedup vs baseline: 1.0661x; 1.0661x over previous
//
#include <hip/hip_runtime.h>

#define NC 50000
#define NG 3000
#define D  64

#define NB_CG 750    // gene bins of 4  (shift 2)
#define NB_GC 782    // cell bins of 64 (shift 6), 782*64 = 50048
#define PBITS 18
#define TILE  4096
#define KTILE (TILE / 256)
#define NPREP 128
#define CAP   4608   // fixed per-bin capacity (mean ~4000, +9.6 sigma for uniform dst)
#define KCAP  ((CAP + 255) / 256)
#define GG_CAP 128   // per-gene gg capacity (mean ~33)
#define OVF_CAP 262144

__device__ inline unsigned short f2bf(float x) {
    unsigned u = __float_as_uint(x);
    unsigned r = u + 0x7FFFu + ((u >> 16) & 1u);
    return (unsigned short)(r >> 16);
}

// unpack a uint4 of 8 bf16 and accumulate (features are pre-weighted)
__device__ __forceinline__ void acc8(const uint4& q, float f[8]) {
    f[0] += __uint_as_float(q.x << 16); f[1] += __uint_as_float(q.x & 0xFFFF0000u);
    f[2] += __uint_as_float(q.y << 16); f[3] += __uint_as_float(q.y & 0xFFFF0000u);
    f[4] += __uint_as_float(q.z << 16); f[5] += __uint_as_float(q.z & 0xFFFF0000u);
    f[6] += __uint_as_float(q.w << 16); f[7] += __uint_as_float(q.w & 0xFFFF0000u);
}

// fp32 fallback row loader: lane l8 holds 8 elements of row s.
__device__ inline void row8f(const float* feat, int s, int l8, float f[8]) {
    const float4* row = (const float4*)(feat + (size_t)s * D);
    const float4 a = row[l8];
    const float4 b = row[l8 + 8];
    f[0] = a.x; f[1] = a.y; f[2] = a.z; f[3] = a.w;
    f[4] = b.x; f[5] = b.y; f[6] = b.z; f[7] = b.w;
}

// ======================= single-pass partition: tiles -> fixed-cap bins =======================
// Edge records are loaded ONCE into registers and reused across hist/placement phases
// (removes the 8B/edge re-read pass). Phases: reg-load+hist -> scan(+reservation) ->
// placement from regs -> coalesced flush.

__global__ __launch_bounds__(256, 6) void partition_kernel(
    const int* __restrict__ src_cg, const int* __restrict__ dst_cg, int e_cg, int nt_cg,
    const int* __restrict__ src_gc, const int* __restrict__ dst_gc, int e_gc, int nt_gc,
    const int* __restrict__ src_gg, const int* __restrict__ dst_gg, int e_gg,
    int* __restrict__ cur_cg, int* __restrict__ cur_gc, int* __restrict__ cnt_gg,
    unsigned* __restrict__ bkt_cg, unsigned* __restrict__ bkt_gc, int* __restrict__ bkt_gg,
    int* __restrict__ ovf_cnt, uint2* __restrict__ ovf,
    const float* __restrict__ cj_cell, const float* __restrict__ mask_exp,
    const float* __restrict__ cj_gene, const float* __restrict__ mask_rev,
    const float* __restrict__ cjj_gene, const float* __restrict__ mask_gg,
    float* __restrict__ w_cell, float* __restrict__ w_rev, float* __restrict__ w_gg,
    const float* __restrict__ c_feat, const float* __restrict__ g_feat,
    unsigned short* __restrict__ wc16, unsigned short* __restrict__ wg16,
    unsigned short* __restrict__ wgg16, int do_cvt)
{
    const int tid = threadIdx.x;
    const int NT2 = nt_cg + nt_gc;

    if (blockIdx.x >= NT2 + 64) {              // ---- prep blocks ----
        const int pb = blockIdx.x - NT2 - 64;
        const long long stride = (long long)NPREP * 256;
        for (long long i = (long long)pb * 256 + tid; i < NC; i += stride)
            w_cell[i] = cj_cell[i] * mask_exp[i];
        for (long long i = (long long)pb * 256 + tid; i < NG; i += stride) {
            w_rev[i] = cj_gene[i] * mask_rev[i];
            w_gg[i]  = cjj_gene[i] * mask_gg[i];
        }
        if (do_cvt) {
            const long long total8 = (long long)(NC + NG) * D / 8;
            for (long long t = (long long)pb * 256 + tid; t < total8; t += stride) {
                const long long base = t * 8;
                if (base < (long long)NC * D) {
                    const int s = (int)(base >> 6);
                    const float w = cj_cell[s] * mask_exp[s];
                    const float4 a = ((const float4*)(c_feat + base))[0];
                    const float4 b = ((const float4*)(c_feat + base))[1];
                    unsigned short* dp = wc16 + base;
                    ((ushort4*)dp)[0] = make_ushort4(f2bf(w*a.x), f2bf(w*a.y), f2bf(w*a.z), f2bf(w*a.w));
                    ((ushort4*)dp)[1] = make_ushort4(f2bf(w*b.x), f2bf(w*b.y), f2bf(w*b.z), f2bf(w*b.w));
                } else {
                    const long long gb = base - (long long)NC * D;
                    const int s = (int)(gb >> 6);
                    const float wr = cj_gene[s] * mask_rev[s];
                    const float wg = cjj_gene[s] * mask_gg[s];
                    const float4 a = ((const float4*)(g_feat + gb))[0];
                    const float4 b = ((const float4*)(g_feat + gb))[1];
                    ((ushort4*)(wg16 + gb))[0]  = make_ushort4(f2bf(wr*a.x), f2bf(wr*a.y), f2bf(wr*a.z), f2bf(wr*a.w));
                    ((ushort4*)(wg16 + gb))[1]  = make_ushort4(f2bf(wr*b.x), f2bf(wr*b.y), f2bf(wr*b.z), f2bf(wr*b.w));
                    ((ushort4*)(wgg16 + gb))[0] = make_ushort4(f2bf(wg*a.x), f2bf(wg*a.y), f2bf(wg*a.z), f2bf(wg*a.w));
                    ((ushort4*)(wgg16 + gb))[1] = make_ushort4(f2bf(wg*b.x), f2bf(wg*b.y), f2bf(wg*b.z), f2bf(wg*b.w));
                }
            }
            if (pb == 0) {                     // zero dummy rows (tail lanes read these)
                for (int i = tid; i < D; i += 256) {
                    wc16[(size_t)NC * D + i] = 0;
                    wg16[(size_t)NG * D + i] = 0;
                    wgg16[(size_t)NG * D + i] = 0;
                }
            }
        }
        return;
    }

    if (blockIdx.x >= NT2) {                   // ---- gg direct partition (64 blocks) ----
        for (long long e = (long long)(blockIdx.x - NT2) * 256 + tid; e < e_gg;
             e += (long long)64 * 256) {
            const int dd = dst_gg[e];
            const int ss = src_gg[e];
            if ((unsigned)dd >= (unsigned)NG || (unsigned)ss >= (unsigned)NG) continue;
            const int pos = atomicAdd(&cnt_gg[dd], 1);
            if (pos < GG_CAP) bkt_gg[dd * GG_CAP + pos] = ss;
            else {
                const int op = atomicAdd(ovf_cnt, 1);
                if (op >= 0 && op < OVF_CAP)
                    ovf[op] = make_uint2((2u << 30) | (unsigned)ss, (unsigned)dd);
            }
        }
        return;
    }

    // ---- tiled partition for cg / gc ----
    const int* src; const int* dst; int ne; int* cur; unsigned* bkt;
    int shift, nbins, t; unsigned rel;
    if (blockIdx.x < nt_cg) { src = src_cg; dst = dst_cg; ne = e_cg; cur = cur_cg; bkt = bkt_cg; shift = 2; nbins = NB_CG; t = blockIdx.x;         rel = 0u; }
    else                    { src = src_gc; dst = dst_gc; ne = e_gc; cur = cur_gc; bkt = bkt_gc; shift = 6; nbins = NB_GC; t = blockIdx.x - nt_cg; rel = 1u; }
    const long long tb = (long long)t * TILE;
    if (tb >= ne) return;
    const int n = (int)((ne - tb) < TILE ? (ne - tb) : TILE);

    __shared__ int th[784];
    __shared__ int toff[784];                  // scan result, then placement cursor
    __shared__ int gs[784];                    // reserved global start within each bin
    __shared__ unsigned staged[TILE];
    const unsigned PMASK = (1u << PBITS) - 1u;
    const unsigned DMASK = (1u << shift) - 1u;

    for (int i = tid; i < nbins; i += 256) th[i] = 0;

    // phase 1: load edge records ONCE into registers, histogram from regs
    int rd[KTILE], rs[KTILE];
    #pragma unroll
    for (int k = 0; k < KTILE; ++k) {
        const int i = k * 256 + tid;
        rd[k] = (i < n) ? dst[tb + i] : -1;    // -1 -> bin OOB -> skipped everywhere
        rs[k] = (i < n) ? src[tb + i] : 0;
    }
    __syncthreads();
    #pragma unroll
    for (int k = 0; k < KTILE; ++k) {
        const unsigned b = ((unsigned)rd[k]) >> shift;
        if (b < (unsigned)nbins) atomicAdd(&th[b], 1);
    }
    __syncthreads();
    if (tid < 64) {                            // exclusive scan th -> toff, fused reservation
        int carry = 0;
        for (int c = 0; c < nbins; c += 64) {
            int idx = c + tid;
            int v = (idx < nbins) ? th[idx] : 0;
            int incl = v;
            #pragma unroll
            for (int d = 1; d < 64; d <<= 1) {
                int x = __shfl_up(incl, d);
                if (tid >= d) incl += x;
            }
            if (idx < nbins) {
                toff[idx] = incl - v + carry;
                gs[idx] = v ? atomicAdd(&cur[idx], v) : 0;
            }
            carry += __shfl(incl, 63);
        }
    }
    __syncthreads();
    #pragma unroll
    for (int k = 0; k < KTILE; ++k) {          // bin-sorted placement from regs (toff = cursor)
        const unsigned d = (unsigned)rd[k];
        const unsigned b = d >> shift;
        if (b < (unsigned)nbins) {
            const int p = atomicAdd(&toff[b], 1);
            if (p >= 0 && p < TILE)
                staged[p] = (b << PBITS) | ((unsigned)rs[k] << shift) | (d & DMASK);
        }
    }
    __syncthreads();
    for (int i = tid; i < n; i += 256) {       // flush contiguous runs to fixed-cap bins
        const unsigned v = staged[i];
        const unsigned b = v >> PBITS;
        if (b < (unsigned)nbins) {
            const int orig = toff[b] - th[b];  // post-placement toff = orig + th
            const int local = gs[b] + (i - orig);
            if (local >= 0 && local < CAP) {
                bkt[(size_t)b * CAP + local] = v & PMASK;
            } else {                           // rare overflow -> spill list
                const unsigned s = (v >> shift) & 0xFFFFu;
                const unsigned dd = (b << shift) | (v & DMASK);
                const int op = atomicAdd(ovf_cnt, 1);
                if (op >= 0 && op < OVF_CAP)
                    ovf[op] = make_uint2((rel << 30) | s, dd);
            }
        }
    }
}

// ======================= fused gather (cg + gg fold | gc), fixed-cap bins =======================
// BF16 path: features are PRE-WEIGHTED bf16 rows; tail lanes read a zero dummy row.
// Bucket records are loaded ONCE into registers for the 64-key counting sort.

template <bool BF16>
__global__ __launch_bounds__(256, 6) void gather3_kernel(
    const unsigned* __restrict__ bkt_cg, const int* __restrict__ cur_cg,
    const unsigned* __restrict__ bkt_gc, const int* __restrict__ cur_gc,
    const void* __restrict__ fc, const void* __restrict__ fg, const void* __restrict__ fgg,
    const float* __restrict__ craw, const float* __restrict__ graw,
    const float* __restrict__ w_cell, const float* __restrict__ w_rev, const float* __restrict__ w_gg,
    const float* __restrict__ ci_gene, const float* __restrict__ cii_gene, const float* __restrict__ ci_cell,
    const int* __restrict__ cnt_gg, const int* __restrict__ bkt_gg,
    const int* __restrict__ ovf_cnt, const uint2* __restrict__ ovf,
    float* __restrict__ g_out, float* __restrict__ c_out)
{
    __shared__ unsigned short sorted[CAP];     // source ids only (16-bit)
    __shared__ int lh[64];                     // hist, then placement cursor (ends = hist)
    __shared__ int loff[64];

    const bool is_cg = (blockIdx.x < NB_CG);
    const int bin = is_cg ? blockIdx.x : blockIdx.x - NB_CG;
    int n = (is_cg ? cur_cg : cur_gc)[bin];
    n = n > CAP ? CAP : n;
    const long long base = (long long)bin * CAP;
    const unsigned* bkt = is_cg ? bkt_cg : bkt_gc;
    const void* feat = is_cg ? fc : fg;
    const float* wsrc = is_cg ? w_cell : w_rev;
    const int shift = is_cg ? 2 : 6;
    const int DIVv = is_cg ? 4 : 64;
    const int KPC  = is_cg ? 16 : 1;           // sort keys per output row
    const int DUM  = is_cg ? NC : NG;          // zero dummy row index
    const int tid  = threadIdx.x;
    const int lane = tid & 63;
    const int wid  = tid >> 6;
    const int grp8 = lane >> 3;                // 8 groups of 8 lanes -> 8 edges in flight
    const int l8   = lane & 7;

    // ---- 64-key counting sort into LDS; records cached in regs across phases ----
    for (int i = tid; i < 64; i += 256) lh[i] = 0;
    unsigned rv[KCAP];
    #pragma unroll
    for (int k = 0; k < KCAP; ++k) {
        const int i = k * 256 + tid;
        rv[k] = (i < n) ? bkt[base + i] : 0xFFFFFFFFu;   // sentinel (valid v < 2^18)
    }
    __syncthreads();
    #pragma unroll
    for (int k = 0; k < KCAP; ++k) {
        const unsigned v = rv[k];
        if (v != 0xFFFFFFFFu) {
            const int kk = is_cg ? (int)(((v & 3u) << 4) | (((v >> 2) & 0xFFFFu) >> 12))
                                 : (int)(v & 63u);
            atomicAdd(&lh[kk], 1);
        }
    }
    __syncthreads();
    if (tid < 64) {
        int v = lh[tid];
        int incl = v;
        #pragma unroll
        for (int d = 1; d < 64; d <<= 1) {
            int t = __shfl_up(incl, d);
            if (tid >= d) incl += t;
        }
        loff[tid] = incl - v;
        lh[tid] = 0;                           // lh -> per-key placement cursor
    }
    __syncthreads();
    #pragma unroll
    for (int k = 0; k < KCAP; ++k) {
        const unsigned v = rv[k];
        if (v != 0xFFFFFFFFu) {
            const int kk = is_cg ? (int)(((v & 3u) << 4) | (((v >> 2) & 0xFFFFu) >> 12))
                                 : (int)(v & 63u);
            const int p = loff[kk] + atomicAdd(&lh[kk], 1);
            if (p >= 0 && p < CAP) sorted[p] = (unsigned short)((v >> shift) & 0xFFFFu);
        }
    }
    __syncthreads();                           // after this, lh[k] == per-key count again

    int novf = *ovf_cnt;
    novf = novf < 0 ? 0 : (novf > OVF_CAP ? OVF_CAP : novf);

    for (int cell = wid; cell < DIVv; cell += 4) {
        const int r = (bin << shift) + cell;
        if (r >= (is_cg ? NG : NC)) continue;

        float fA[8] = {0.f, 0.f, 0.f, 0.f, 0.f, 0.f, 0.f, 0.f};
        {
            const int k0 = cell * KPC, k1 = k0 + KPC - 1;
            const int lo = loff[k0], hi = loff[k1] + lh[k1];
            if (BF16) {
                const uint4* fp = (const uint4*)feat;
                for (int jj = lo; jj < hi; jj += 32) {   // 4 rows in flight per group
                    const int b0 = jj + grp8;
                    const int s0 = (b0      < hi) ? (int)sorted[b0]      : DUM;
                    const int s1 = (b0 + 8  < hi) ? (int)sorted[b0 + 8]  : DUM;
                    const int s2 = (b0 + 16 < hi) ? (int)sorted[b0 + 16] : DUM;
                    const int s3 = (b0 + 24 < hi) ? (int)sorted[b0 + 24] : DUM;
                    const uint4 q0 = fp[(size_t)s0 * 8 + l8];
                    const uint4 q1 = fp[(size_t)s1 * 8 + l8];
                    const uint4 q2 = fp[(size_t)s2 * 8 + l8];
                    const uint4 q3 = fp[(size_t)s3 * 8 + l8];
                    acc8(q0, fA); acc8(q1, fA); acc8(q2, fA); acc8(q3, fA);
                }
            } else {
                for (int jj = lo; jj < hi; jj += 8) {
                    const int j = jj + grp8;
                    const bool valid = (j < hi);
                    const int s = valid ? (int)sorted[j] : 0;
                    const float w = valid ? wsrc[s] : 0.0f;
                    float f[8]; row8f((const float*)feat, s, l8, f);
                    #pragma unroll
                    for (int q = 0; q < 8; ++q) fA[q] += w * f[q];
                }
            }
        }

        float fB[8] = {0.f, 0.f, 0.f, 0.f, 0.f, 0.f, 0.f, 0.f};
        if (is_cg) {
            int ngg = cnt_gg[r];
            ngg = ngg > GG_CAP ? GG_CAP : ngg;
            const int* bg = bkt_gg + (size_t)r * GG_CAP;
            if (BF16) {
                const uint4* fp = (const uint4*)fgg;
                for (int jj = 0; jj < ngg; jj += 16) {   // 2 rows in flight
                    const int j0 = jj + grp8;
                    const int j1 = jj + 8 + grp8;
                    const int s0 = (j0 < ngg) ? bg[j0] : NG;
                    const int s1 = (j1 < ngg) ? bg[j1] : NG;
                    const uint4 q0 = fp[(size_t)s0 * 8 + l8];
                    const uint4 q1 = fp[(size_t)s1 * 8 + l8];
                    acc8(q0, fB); acc8(q1, fB);
                }
            } else {
                for (int jj = 0; jj < ngg; jj += 8) {
                    const int j = jj + grp8;
                    const bool valid = (j < ngg);
                    const int s = valid ? bg[j] : 0;
                    const float w = valid ? w_gg[s] : 0.0f;
                    float f[8]; row8f(graw, s, l8, f);
                    #pragma unroll
                    for (int q = 0; q < 8; ++q) fB[q] += w * f[q];
                }
            }
        }

        #pragma unroll
        for (int q = 0; q < 8; ++q) {
            #pragma unroll
            for (int off = 8; off < 64; off <<= 1) fA[q] += __shfl_xor(fA[q], off);
        }
        if (is_cg) {
            #pragma unroll
            for (int q = 0; q < 8; ++q) {
                #pragma unroll
                for (int off = 8; off < 64; off <<= 1) fB[q] += __shfl_xor(fB[q], off);
            }
        }

        if (grp8 == 0) {
            float o[8];
            float* outp;
            if (is_cg) {
                const float sa = 0.5f * ci_gene[r];
                const float sb = 0.5f * cii_gene[r];
                outp = g_out + (size_t)r * D;
                #pragma unroll
                for (int q = 0; q < 8; ++q) o[q] = sa * fA[q] + sb * fB[q];
            } else {
                const float sc = ci_cell[r];
                outp = c_out + (size_t)r * D;
                #pragma unroll
                for (int q = 0; q < 8; ++q) o[q] = sc * fA[q];
            }

            if (novf > 0) {                    // fold rare overflow edges for this row
                for (int e = 0; e < novf; ++e) {
                    const uint2 vv = ovf[e];
                    const int d = (int)vv.y;
                    if (d != r) continue;
                    const unsigned relv = vv.x >> 30;
                    const int s = (int)(vv.x & 0x3FFFFFFFu);
                    const float* fr = nullptr; float w = 0.f;
                    if (is_cg) {
                        if (relv == 0u && s < NC)      { fr = craw + (size_t)s * D; w = 0.5f * ci_gene[r] * w_cell[s]; }
                        else if (relv == 2u && s < NG) { fr = graw + (size_t)s * D; w = 0.5f * cii_gene[r] * w_gg[s]; }
                    } else {
                        if (relv == 1u && s < NG)      { fr = graw + (size_t)s * D; w = ci_cell[r] * w_rev[s]; }
                    }
                    if (fr) {
                        #pragma unroll
                        for (int q = 0; q < 8; ++q) {
                            const int elem = BF16 ? (8 * l8 + q)
                                                  : (q < 4 ? 4 * l8 + q : 32 + 4 * l8 + (q - 4));
                            o[q] += w * fr[elem];
                        }
                    }
                }
            }

            if (BF16) {
                *(float4*)(outp + 8 * l8)     = make_float4(o[0], o[1], o[2], o[3]);
                *(float4*)(outp + 8 * l8 + 4) = make_float4(o[4], o[5], o[6], o[7]);
            } else {
                *(float4*)(outp + 4 * l8)      = make_float4(o[0], o[1], o[2], o[3]);
                *(float4*)(outp + 32 + 4 * l8) = make_float4(o[4], o[5], o[6], o[7]);
            }
        }
    }
}

// ======================= fallback (atomic scatter) =======================

__global__ __launch_bounds__(256) void edge_scatter_kernel(
    const float* __restrict__ feat, const float* __restrict__ cj,
    const float* __restrict__ mask, const float* __restrict__ ci,
    const int* __restrict__ src, const int* __restrict__ dst,
    float* __restrict__ out, int nedges, float alpha)
{
    const int lane16 = threadIdx.x & 15;
    const int eloc   = threadIdx.x >> 4;
    const long long e = (long long)blockIdx.x * 16 + eloc;
    if (e >= nedges) return;
    const int s = src[e];
    const int t = dst[e];
    const float w = cj[s] * mask[s] * ci[t] * alpha;
    const float4 v = *(const float4*)(feat + (size_t)s * D + lane16 * 4);
    float* o = out + (size_t)t * D + lane16 * 4;
#if defined(__HIP_DEVICE_COMPILE__)
    unsafeAtomicAdd(o + 0, w * v.x);
    unsafeAtomicAdd(o + 1, w * v.y);
    unsafeAtomicAdd(o + 2, w * v.z);
    unsafeAtomicAdd(o + 3, w * v.w);
#endif
}

// ======================= launch =======================

extern "C" void kernel_launch(void* const* d_in, const int* in_sizes, int n_in,
                              void* d_out, int out_size, void* d_ws, size_t ws_size,
                              hipStream_t stream)
{
    const float* c_feat   = (const float*)d_in[0];
    const float* g_feat   = (const float*)d_in[1];
    const float* cj_cell  = (const float*)d_in[2];
    const float* ci_cell  = (const float*)d_in[3];
    const float* cj_gene  = (const float*)d_in[4];
    const float* ci_gene  = (const float*)d_in[5];
    const float* cjj_gene = (const float*)d_in[6];
    const float* cii_gene = (const float*)d_in[7];
    const float* mask_exp = (const float*)d_in[8];
    const float* mask_rev = (const float*)d_in[9];
    const float* mask_gg  = (const float*)d_in[10];
    const int*   src_cg   = (const int*)d_in[11];
    const int*   dst_cg   = (const int*)d_in[12];
    const int*   src_gc   = (const int*)d_in[13];
    const int*   dst_gc   = (const int*)d_in[14];
    const int*   src_gg   = (const int*)d_in[15];
    const int*   dst_gg   = (const int*)d_in[16];

    const int e_cg = in_sizes[11];
    const int e_gc = in_sizes[13];
    const int e_gg = in_sizes[15];

    float* c_out = (float*)d_out;                   // [NC, D]
    float* g_out = (float*)d_out + (size_t)NC * D;  // [NG, D]

    const int nt_cg = (e_cg + TILE - 1) / TILE;
    const int nt_gc = (e_gc + TILE - 1) / TILE;

    // ---- workspace layout (int units) ----
    int* ws = (int*)d_ws;
    size_t p = 0;
    int* cur_cg  = ws + p; p += NB_CG;       // memset region start
    int* cur_gc  = ws + p; p += NB_GC;
    int* cnt_gg  = ws + p; p += NG;
    int* ovf_cnt = ws + p; p += 1;           // memset region end
    const size_t zcount = p;
    float* w_cell = (float*)(ws + p); p += NC;
    float* w_rev  = (float*)(ws + p); p += NG;
    float* w_gg   = (float*)(ws + p); p += NG;
    unsigned* bkt_cg = (unsigned*)(ws + p); p += (size_t)NB_CG * CAP;
    unsigned* bkt_gc = (unsigned*)(ws + p); p += (size_t)NB_GC * CAP;
    int* bkt_gg = ws + p; p += (size_t)NG * GG_CAP;
    p = (p + 1) & ~(size_t)1;                // 8B align for uint2
    uint2* ovf = (uint2*)(ws + p); p += (size_t)OVF_CAP * 2;
    const size_t need_base = p * sizeof(int);
    p = (p + 3) & ~(size_t)3;                // 16B align for uint4 reads
    unsigned short* wc16  = (unsigned short*)(ws + p); p += (size_t)(NC + 1) * D / 2;
    unsigned short* wg16  = (unsigned short*)(ws + p); p += (size_t)(NG + 1) * D / 2;
    unsigned short* wgg16 = (unsigned short*)(ws + p); p += (size_t)(NG + 1) * D / 2;
    const size_t need_full = p * sizeof(int);

    // fallback if workspace too small or sizes pathological for fixed-cap bins
    if (need_base > ws_size || e_cg > 3200000 || e_gc > 3200000 || e_gg > 200000) {
        hipMemsetAsync(d_out, 0, (size_t)out_size * sizeof(float), stream);
        edge_scatter_kernel<<<(e_cg + 15) / 16, 256, 0, stream>>>(
            c_feat, cj_cell, mask_exp, ci_gene, src_cg, dst_cg, g_out, e_cg, 0.5f);
        edge_scatter_kernel<<<(e_gc + 15) / 16, 256, 0, stream>>>(
            g_feat, cj_gene, mask_rev, ci_cell, src_gc, dst_gc, c_out, e_gc, 1.0f);
        edge_scatter_kernel<<<(e_gg + 15) / 16, 256, 0, stream>>>(
            g_feat, cjj_gene, mask_gg, cii_gene, src_gg, dst_gg, g_out, e_gg, 0.5f);
        return;
    }
    const int use_bf16 = (need_full <= ws_size) ? 1 : 0;

    hipMemsetAsync(ws, 0, zcount * sizeof(int), stream);

    partition_kernel<<<nt_cg + nt_gc + 64 + NPREP, 256, 0, stream>>>(
        src_cg, dst_cg, e_cg, nt_cg,
        src_gc, dst_gc, e_gc, nt_gc,
        src_gg, dst_gg, e_gg,
        cur_cg, cur_gc, cnt_gg,
        bkt_cg, bkt_gc, bkt_gg,
        ovf_cnt, ovf,
        cj_cell, mask_exp, cj_gene, mask_rev, cjj_gene, mask_gg,
        w_cell, w_rev, w_gg, c_feat, g_feat, wc16, wg16, wgg16, use_bf16);

    if (use_bf16) {
        gather3_kernel<true><<<NB_CG + NB_GC, 256, 0, stream>>>(
            bkt_cg, cur_cg, bkt_gc, cur_gc,
            (const void*)wc16, (const void*)wg16, (const void*)wgg16,
            c_feat, g_feat,
            w_cell, w_rev, w_gg, ci_gene, cii_gene, ci_cell,
            cnt_gg, bkt_gg, ovf_cnt, ovf, g_out, c_out);
    } else {
        gather3_kernel<false><<<NB_CG + NB_GC, 256, 0, stream>>>(
            bkt_cg, cur_cg, bkt_gc, cur_gc,
            (const void*)c_feat, (const void*)g_feat, (const void*)g_feat,
            c_feat, g_feat,
            w_cell, w_rev, w_gg, ci_gene, cii_gene, ci_cell,
            cnt_gg, bkt_gg, ovf_cnt, ovf, g_out, c_out);
    }
}

// Round 6
// 250.799 us; speedup vs baseline: 1.0721x; 1.0057x over previous
//
#include <hip/hip_runtime.h>

#define NC 50000
#define NG 3000
#define D  64

#define NB_CG 750    // gene bins of 4  (shift 2)
#define NB_GC 782    // cell bins of 64 (shift 6), 782*64 = 50048
#define PBITS 18
#define TILE  4096
#define KTILE (TILE / 256)
#define NPREP 128
#define CAP   4608   // fixed per-bin capacity (mean ~4000, +9.6 sigma for uniform dst)
#define KCAP  ((CAP + 255) / 256)
#define GG_CAP 128   // per-gene gg capacity (mean ~33)
#define OVF_CAP 262144

__device__ inline unsigned short f2bf(float x) {
    unsigned u = __float_as_uint(x);
    unsigned r = u + 0x7FFFu + ((u >> 16) & 1u);
    return (unsigned short)(r >> 16);
}

// unpack a uint4 of 8 bf16 and accumulate (features are pre-weighted)
__device__ __forceinline__ void acc8(const uint4& q, float f[8]) {
    f[0] += __uint_as_float(q.x << 16); f[1] += __uint_as_float(q.x & 0xFFFF0000u);
    f[2] += __uint_as_float(q.y << 16); f[3] += __uint_as_float(q.y & 0xFFFF0000u);
    f[4] += __uint_as_float(q.z << 16); f[5] += __uint_as_float(q.z & 0xFFFF0000u);
    f[6] += __uint_as_float(q.w << 16); f[7] += __uint_as_float(q.w & 0xFFFF0000u);
}

// fp32 fallback row loader: lane l8 holds 8 elements of row s.
__device__ inline void row8f(const float* feat, int s, int l8, float f[8]) {
    const float4* row = (const float4*)(feat + (size_t)s * D);
    const float4 a = row[l8];
    const float4 b = row[l8 + 8];
    f[0] = a.x; f[1] = a.y; f[2] = a.z; f[3] = a.w;
    f[4] = b.x; f[5] = b.y; f[6] = b.z; f[7] = b.w;
}

// ======================= single-pass partition: tiles -> fixed-cap bins =======================
// Edge records are loaded ONCE into registers and reused across hist/placement phases.
// Phases: reg-load+hist -> scan(+reservation) -> placement from regs -> coalesced flush.

__global__ __launch_bounds__(256, 6) void partition_kernel(
    const int* __restrict__ src_cg, const int* __restrict__ dst_cg, int e_cg, int nt_cg,
    const int* __restrict__ src_gc, const int* __restrict__ dst_gc, int e_gc, int nt_gc,
    const int* __restrict__ src_gg, const int* __restrict__ dst_gg, int e_gg,
    int* __restrict__ cur_cg, int* __restrict__ cur_gc, int* __restrict__ cnt_gg,
    unsigned* __restrict__ bkt_cg, unsigned* __restrict__ bkt_gc, int* __restrict__ bkt_gg,
    int* __restrict__ ovf_cnt, uint2* __restrict__ ovf,
    const float* __restrict__ cj_cell, const float* __restrict__ mask_exp,
    const float* __restrict__ cj_gene, const float* __restrict__ mask_rev,
    const float* __restrict__ cjj_gene, const float* __restrict__ mask_gg,
    float* __restrict__ w_cell, float* __restrict__ w_rev, float* __restrict__ w_gg,
    const float* __restrict__ c_feat, const float* __restrict__ g_feat,
    unsigned short* __restrict__ wc16, unsigned short* __restrict__ wg16,
    unsigned short* __restrict__ wgg16, int do_cvt)
{
    const int tid = threadIdx.x;
    const int NT2 = nt_cg + nt_gc;

    if (blockIdx.x >= NT2 + 64) {              // ---- prep blocks ----
        const int pb = blockIdx.x - NT2 - 64;
        const long long stride = (long long)NPREP * 256;
        for (long long i = (long long)pb * 256 + tid; i < NC; i += stride)
            w_cell[i] = cj_cell[i] * mask_exp[i];
        for (long long i = (long long)pb * 256 + tid; i < NG; i += stride) {
            w_rev[i] = cj_gene[i] * mask_rev[i];
            w_gg[i]  = cjj_gene[i] * mask_gg[i];
        }
        if (do_cvt) {
            const long long total8 = (long long)(NC + NG) * D / 8;
            for (long long t = (long long)pb * 256 + tid; t < total8; t += stride) {
                const long long base = t * 8;
                if (base < (long long)NC * D) {
                    const int s = (int)(base >> 6);
                    const float w = cj_cell[s] * mask_exp[s];
                    const float4 a = ((const float4*)(c_feat + base))[0];
                    const float4 b = ((const float4*)(c_feat + base))[1];
                    unsigned short* dp = wc16 + base;
                    ((ushort4*)dp)[0] = make_ushort4(f2bf(w*a.x), f2bf(w*a.y), f2bf(w*a.z), f2bf(w*a.w));
                    ((ushort4*)dp)[1] = make_ushort4(f2bf(w*b.x), f2bf(w*b.y), f2bf(w*b.z), f2bf(w*b.w));
                } else {
                    const long long gb = base - (long long)NC * D;
                    const int s = (int)(gb >> 6);
                    const float wr = cj_gene[s] * mask_rev[s];
                    const float wg = cjj_gene[s] * mask_gg[s];
                    const float4 a = ((const float4*)(g_feat + gb))[0];
                    const float4 b = ((const float4*)(g_feat + gb))[1];
                    ((ushort4*)(wg16 + gb))[0]  = make_ushort4(f2bf(wr*a.x), f2bf(wr*a.y), f2bf(wr*a.z), f2bf(wr*a.w));
                    ((ushort4*)(wg16 + gb))[1]  = make_ushort4(f2bf(wr*b.x), f2bf(wr*b.y), f2bf(wr*b.z), f2bf(wr*b.w));
                    ((ushort4*)(wgg16 + gb))[0] = make_ushort4(f2bf(wg*a.x), f2bf(wg*a.y), f2bf(wg*a.z), f2bf(wg*a.w));
                    ((ushort4*)(wgg16 + gb))[1] = make_ushort4(f2bf(wg*b.x), f2bf(wg*b.y), f2bf(wg*b.z), f2bf(wg*b.w));
                }
            }
            if (pb == 0) {                     // zero dummy rows (tail lanes read these)
                for (int i = tid; i < D; i += 256) {
                    wc16[(size_t)NC * D + i] = 0;
                    wg16[(size_t)NG * D + i] = 0;
                    wgg16[(size_t)NG * D + i] = 0;
                }
            }
        }
        return;
    }

    if (blockIdx.x >= NT2) {                   // ---- gg direct partition (64 blocks) ----
        for (long long e = (long long)(blockIdx.x - NT2) * 256 + tid; e < e_gg;
             e += (long long)64 * 256) {
            const int dd = dst_gg[e];
            const int ss = src_gg[e];
            if ((unsigned)dd >= (unsigned)NG || (unsigned)ss >= (unsigned)NG) continue;
            const int pos = atomicAdd(&cnt_gg[dd], 1);
            if (pos < GG_CAP) bkt_gg[dd * GG_CAP + pos] = ss;
            else {
                const int op = atomicAdd(ovf_cnt, 1);
                if (op >= 0 && op < OVF_CAP)
                    ovf[op] = make_uint2((2u << 30) | (unsigned)ss, (unsigned)dd);
            }
        }
        return;
    }

    // ---- tiled partition for cg / gc ----
    const int* src; const int* dst; int ne; int* cur; unsigned* bkt;
    int shift, nbins, t; unsigned rel;
    if (blockIdx.x < nt_cg) { src = src_cg; dst = dst_cg; ne = e_cg; cur = cur_cg; bkt = bkt_cg; shift = 2; nbins = NB_CG; t = blockIdx.x;         rel = 0u; }
    else                    { src = src_gc; dst = dst_gc; ne = e_gc; cur = cur_gc; bkt = bkt_gc; shift = 6; nbins = NB_GC; t = blockIdx.x - nt_cg; rel = 1u; }
    const long long tb = (long long)t * TILE;
    if (tb >= ne) return;
    const int n = (int)((ne - tb) < TILE ? (ne - tb) : TILE);

    __shared__ int th[784];
    __shared__ int toff[784];                  // scan result, then placement cursor
    __shared__ int gs[784];                    // reserved global start within each bin
    __shared__ unsigned staged[TILE];
    const unsigned PMASK = (1u << PBITS) - 1u;
    const unsigned DMASK = (1u << shift) - 1u;

    for (int i = tid; i < nbins; i += 256) th[i] = 0;

    // phase 1: load edge records ONCE into registers, histogram from regs
    int rd[KTILE], rs[KTILE];
    #pragma unroll
    for (int k = 0; k < KTILE; ++k) {
        const int i = k * 256 + tid;
        rd[k] = (i < n) ? dst[tb + i] : -1;    // -1 -> bin OOB -> skipped everywhere
        rs[k] = (i < n) ? src[tb + i] : 0;
    }
    __syncthreads();
    #pragma unroll
    for (int k = 0; k < KTILE; ++k) {
        const unsigned b = ((unsigned)rd[k]) >> shift;
        if (b < (unsigned)nbins) atomicAdd(&th[b], 1);
    }
    __syncthreads();
    if (tid < 64) {                            // exclusive scan th -> toff, fused reservation
        int carry = 0;
        for (int c = 0; c < nbins; c += 64) {
            int idx = c + tid;
            int v = (idx < nbins) ? th[idx] : 0;
            int incl = v;
            #pragma unroll
            for (int d = 1; d < 64; d <<= 1) {
                int x = __shfl_up(incl, d);
                if (tid >= d) incl += x;
            }
            if (idx < nbins) {
                toff[idx] = incl - v + carry;
                gs[idx] = v ? atomicAdd(&cur[idx], v) : 0;
            }
            carry += __shfl(incl, 63);
        }
    }
    __syncthreads();
    #pragma unroll
    for (int k = 0; k < KTILE; ++k) {          // bin-sorted placement from regs (toff = cursor)
        const unsigned d = (unsigned)rd[k];
        const unsigned b = d >> shift;
        if (b < (unsigned)nbins) {
            const int p = atomicAdd(&toff[b], 1);
            if (p >= 0 && p < TILE)
                staged[p] = (b << PBITS) | ((unsigned)rs[k] << shift) | (d & DMASK);
        }
    }
    __syncthreads();
    for (int i = tid; i < n; i += 256) {       // flush contiguous runs to fixed-cap bins
        const unsigned v = staged[i];
        const unsigned b = v >> PBITS;
        if (b < (unsigned)nbins) {
            const int orig = toff[b] - th[b];  // post-placement toff = orig + th
            const int local = gs[b] + (i - orig);
            if (local >= 0 && local < CAP) {
                bkt[(size_t)b * CAP + local] = v & PMASK;
            } else {                           // rare overflow -> spill list
                const unsigned s = (v >> shift) & 0xFFFFu;
                const unsigned dd = (b << shift) | (v & DMASK);
                const int op = atomicAdd(ovf_cnt, 1);
                if (op >= 0 && op < OVF_CAP)
                    ovf[op] = make_uint2((rel << 30) | s, dd);
            }
        }
    }
}

// ======================= fused gather (cg + gg fold | gc), fixed-cap bins =======================
// BF16 path: features are PRE-WEIGHTED bf16 rows; tail lanes read a zero dummy row.
// fA loop: 8 rows in flight per 8-lane group, DUAL accumulator chains (fA/fA2) so the
// compiler cannot collapse the loads into a serial load->add chain (VGPR 28 symptom).

template <bool BF16>
__global__ __launch_bounds__(256, 6) void gather3_kernel(
    const unsigned* __restrict__ bkt_cg, const int* __restrict__ cur_cg,
    const unsigned* __restrict__ bkt_gc, const int* __restrict__ cur_gc,
    const void* __restrict__ fc, const void* __restrict__ fg, const void* __restrict__ fgg,
    const float* __restrict__ craw, const float* __restrict__ graw,
    const float* __restrict__ w_cell, const float* __restrict__ w_rev, const float* __restrict__ w_gg,
    const float* __restrict__ ci_gene, const float* __restrict__ cii_gene, const float* __restrict__ ci_cell,
    const int* __restrict__ cnt_gg, const int* __restrict__ bkt_gg,
    const int* __restrict__ ovf_cnt, const uint2* __restrict__ ovf,
    float* __restrict__ g_out, float* __restrict__ c_out)
{
    __shared__ unsigned short sorted[CAP];     // source ids only (16-bit)
    __shared__ int lh[64];                     // hist, then placement cursor (ends = hist)
    __shared__ int loff[64];

    const bool is_cg = (blockIdx.x < NB_CG);
    const int bin = is_cg ? blockIdx.x : blockIdx.x - NB_CG;
    int n = (is_cg ? cur_cg : cur_gc)[bin];
    n = n > CAP ? CAP : n;
    const long long base = (long long)bin * CAP;
    const unsigned* bkt = is_cg ? bkt_cg : bkt_gc;
    const void* feat = is_cg ? fc : fg;
    const float* wsrc = is_cg ? w_cell : w_rev;
    const int shift = is_cg ? 2 : 6;
    const int DIVv = is_cg ? 4 : 64;
    const int KPC  = is_cg ? 16 : 1;           // sort keys per output row
    const int DUM  = is_cg ? NC : NG;          // zero dummy row index
    const int tid  = threadIdx.x;
    const int lane = tid & 63;
    const int wid  = tid >> 6;
    const int grp8 = lane >> 3;                // 8 groups of 8 lanes
    const int l8   = lane & 7;

    // ---- 64-key counting sort into LDS; records cached in regs across phases ----
    for (int i = tid; i < 64; i += 256) lh[i] = 0;
    unsigned rv[KCAP];
    #pragma unroll
    for (int k = 0; k < KCAP; ++k) {
        const int i = k * 256 + tid;
        rv[k] = (i < n) ? bkt[base + i] : 0xFFFFFFFFu;   // sentinel (valid v < 2^18)
    }
    __syncthreads();
    #pragma unroll
    for (int k = 0; k < KCAP; ++k) {
        const unsigned v = rv[k];
        if (v != 0xFFFFFFFFu) {
            const int kk = is_cg ? (int)(((v & 3u) << 4) | (((v >> 2) & 0xFFFFu) >> 12))
                                 : (int)(v & 63u);
            atomicAdd(&lh[kk], 1);
        }
    }
    __syncthreads();
    if (tid < 64) {
        int v = lh[tid];
        int incl = v;
        #pragma unroll
        for (int d = 1; d < 64; d <<= 1) {
            int t = __shfl_up(incl, d);
            if (tid >= d) incl += t;
        }
        loff[tid] = incl - v;
        lh[tid] = 0;                           // lh -> per-key placement cursor
    }
    __syncthreads();
    #pragma unroll
    for (int k = 0; k < KCAP; ++k) {
        const unsigned v = rv[k];
        if (v != 0xFFFFFFFFu) {
            const int kk = is_cg ? (int)(((v & 3u) << 4) | (((v >> 2) & 0xFFFFu) >> 12))
                                 : (int)(v & 63u);
            const int p = loff[kk] + atomicAdd(&lh[kk], 1);
            if (p >= 0 && p < CAP) sorted[p] = (unsigned short)((v >> shift) & 0xFFFFu);
        }
    }
    __syncthreads();                           // after this, lh[k] == per-key count again

    int novf = *ovf_cnt;
    novf = novf < 0 ? 0 : (novf > OVF_CAP ? OVF_CAP : novf);

    for (int cell = wid; cell < DIVv; cell += 4) {
        const int r = (bin << shift) + cell;
        if (r >= (is_cg ? NG : NC)) continue;

        float fA[8]  = {0.f, 0.f, 0.f, 0.f, 0.f, 0.f, 0.f, 0.f};
        float fA2[8] = {0.f, 0.f, 0.f, 0.f, 0.f, 0.f, 0.f, 0.f};
        {
            const int k0 = cell * KPC, k1 = k0 + KPC - 1;
            const int lo = loff[k0], hi = loff[k1] + lh[k1];
            if (BF16) {
                const uint4* fp = (const uint4*)feat;
                for (int jj = lo; jj < hi; jj += 64) {   // 8 rows in flight per group
                    const int b0 = jj + grp8;
                    const int s0 = (b0      < hi) ? (int)sorted[b0]      : DUM;
                    const int s1 = (b0 + 8  < hi) ? (int)sorted[b0 + 8]  : DUM;
                    const int s2 = (b0 + 16 < hi) ? (int)sorted[b0 + 16] : DUM;
                    const int s3 = (b0 + 24 < hi) ? (int)sorted[b0 + 24] : DUM;
                    const int s4 = (b0 + 32 < hi) ? (int)sorted[b0 + 32] : DUM;
                    const int s5 = (b0 + 40 < hi) ? (int)sorted[b0 + 40] : DUM;
                    const int s6 = (b0 + 48 < hi) ? (int)sorted[b0 + 48] : DUM;
                    const int s7 = (b0 + 56 < hi) ? (int)sorted[b0 + 56] : DUM;
                    const uint4 q0 = fp[(size_t)s0 * 8 + l8];
                    const uint4 q1 = fp[(size_t)s1 * 8 + l8];
                    const uint4 q2 = fp[(size_t)s2 * 8 + l8];
                    const uint4 q3 = fp[(size_t)s3 * 8 + l8];
                    const uint4 q4 = fp[(size_t)s4 * 8 + l8];
                    const uint4 q5 = fp[(size_t)s5 * 8 + l8];
                    const uint4 q6 = fp[(size_t)s6 * 8 + l8];
                    const uint4 q7 = fp[(size_t)s7 * 8 + l8];
                    acc8(q0, fA);  acc8(q1, fA2);
                    acc8(q2, fA);  acc8(q3, fA2);
                    acc8(q4, fA);  acc8(q5, fA2);
                    acc8(q6, fA);  acc8(q7, fA2);
                }
            } else {
                for (int jj = lo; jj < hi; jj += 8) {
                    const int j = jj + grp8;
                    const bool valid = (j < hi);
                    const int s = valid ? (int)sorted[j] : 0;
                    const float w = valid ? wsrc[s] : 0.0f;
                    float f[8]; row8f((const float*)feat, s, l8, f);
                    #pragma unroll
                    for (int q = 0; q < 8; ++q) fA[q] += w * f[q];
                }
            }
        }
        #pragma unroll
        for (int q = 0; q < 8; ++q) fA[q] += fA2[q];

        float fB[8] = {0.f, 0.f, 0.f, 0.f, 0.f, 0.f, 0.f, 0.f};
        if (is_cg) {
            int ngg = cnt_gg[r];
            ngg = ngg > GG_CAP ? GG_CAP : ngg;
            const int* bg = bkt_gg + (size_t)r * GG_CAP;
            if (BF16) {
                const uint4* fp = (const uint4*)fgg;
                for (int jj = 0; jj < ngg; jj += 16) {   // 2 rows in flight
                    const int j0 = jj + grp8;
                    const int j1 = jj + 8 + grp8;
                    const int s0 = (j0 < ngg) ? bg[j0] : NG;
                    const int s1 = (j1 < ngg) ? bg[j1] : NG;
                    const uint4 q0 = fp[(size_t)s0 * 8 + l8];
                    const uint4 q1 = fp[(size_t)s1 * 8 + l8];
                    acc8(q0, fB); acc8(q1, fB);
                }
            } else {
                for (int jj = 0; jj < ngg; jj += 8) {
                    const int j = jj + grp8;
                    const bool valid = (j < ngg);
                    const int s = valid ? bg[j] : 0;
                    const float w = valid ? w_gg[s] : 0.0f;
                    float f[8]; row8f(graw, s, l8, f);
                    #pragma unroll
                    for (int q = 0; q < 8; ++q) fB[q] += w * f[q];
                }
            }
        }

        #pragma unroll
        for (int q = 0; q < 8; ++q) {
            #pragma unroll
            for (int off = 8; off < 64; off <<= 1) fA[q] += __shfl_xor(fA[q], off);
        }
        if (is_cg) {
            #pragma unroll
            for (int q = 0; q < 8; ++q) {
                #pragma unroll
                for (int off = 8; off < 64; off <<= 1) fB[q] += __shfl_xor(fB[q], off);
            }
        }

        if (grp8 == 0) {
            float o[8];
            float* outp;
            if (is_cg) {
                const float sa = 0.5f * ci_gene[r];
                const float sb = 0.5f * cii_gene[r];
                outp = g_out + (size_t)r * D;
                #pragma unroll
                for (int q = 0; q < 8; ++q) o[q] = sa * fA[q] + sb * fB[q];
            } else {
                const float sc = ci_cell[r];
                outp = c_out + (size_t)r * D;
                #pragma unroll
                for (int q = 0; q < 8; ++q) o[q] = sc * fA[q];
            }

            if (novf > 0) {                    // fold rare overflow edges for this row
                for (int e = 0; e < novf; ++e) {
                    const uint2 vv = ovf[e];
                    const int d = (int)vv.y;
                    if (d != r) continue;
                    const unsigned relv = vv.x >> 30;
                    const int s = (int)(vv.x & 0x3FFFFFFFu);
                    const float* fr = nullptr; float w = 0.f;
                    if (is_cg) {
                        if (relv == 0u && s < NC)      { fr = craw + (size_t)s * D; w = 0.5f * ci_gene[r] * w_cell[s]; }
                        else if (relv == 2u && s < NG) { fr = graw + (size_t)s * D; w = 0.5f * cii_gene[r] * w_gg[s]; }
                    } else {
                        if (relv == 1u && s < NG)      { fr = graw + (size_t)s * D; w = ci_cell[r] * w_rev[s]; }
                    }
                    if (fr) {
                        #pragma unroll
                        for (int q = 0; q < 8; ++q) {
                            const int elem = BF16 ? (8 * l8 + q)
                                                  : (q < 4 ? 4 * l8 + q : 32 + 4 * l8 + (q - 4));
                            o[q] += w * fr[elem];
                        }
                    }
                }
            }

            if (BF16) {
                *(float4*)(outp + 8 * l8)     = make_float4(o[0], o[1], o[2], o[3]);
                *(float4*)(outp + 8 * l8 + 4) = make_float4(o[4], o[5], o[6], o[7]);
            } else {
                *(float4*)(outp + 4 * l8)      = make_float4(o[0], o[1], o[2], o[3]);
                *(float4*)(outp + 32 + 4 * l8) = make_float4(o[4], o[5], o[6], o[7]);
            }
        }
    }
}

// ======================= fallback (atomic scatter) =======================

__global__ __launch_bounds__(256) void edge_scatter_kernel(
    const float* __restrict__ feat, const float* __restrict__ cj,
    const float* __restrict__ mask, const float* __restrict__ ci,
    const int* __restrict__ src, const int* __restrict__ dst,
    float* __restrict__ out, int nedges, float alpha)
{
    const int lane16 = threadIdx.x & 15;
    const int eloc   = threadIdx.x >> 4;
    const long long e = (long long)blockIdx.x * 16 + eloc;
    if (e >= nedges) return;
    const int s = src[e];
    const int t = dst[e];
    const float w = cj[s] * mask[s] * ci[t] * alpha;
    const float4 v = *(const float4*)(feat + (size_t)s * D + lane16 * 4);
    float* o = out + (size_t)t * D + lane16 * 4;
#if defined(__HIP_DEVICE_COMPILE__)
    unsafeAtomicAdd(o + 0, w * v.x);
    unsafeAtomicAdd(o + 1, w * v.y);
    unsafeAtomicAdd(o + 2, w * v.z);
    unsafeAtomicAdd(o + 3, w * v.w);
#endif
}

// ======================= launch =======================

extern "C" void kernel_launch(void* const* d_in, const int* in_sizes, int n_in,
                              void* d_out, int out_size, void* d_ws, size_t ws_size,
                              hipStream_t stream)
{
    const float* c_feat   = (const float*)d_in[0];
    const float* g_feat   = (const float*)d_in[1];
    const float* cj_cell  = (const float*)d_in[2];
    const float* ci_cell  = (const float*)d_in[3];
    const float* cj_gene  = (const float*)d_in[4];
    const float* ci_gene  = (const float*)d_in[5];
    const float* cjj_gene = (const float*)d_in[6];
    const float* cii_gene = (const float*)d_in[7];
    const float* mask_exp = (const float*)d_in[8];
    const float* mask_rev = (const float*)d_in[9];
    const float* mask_gg  = (const float*)d_in[10];
    const int*   src_cg   = (const int*)d_in[11];
    const int*   dst_cg   = (const int*)d_in[12];
    const int*   src_gc   = (const int*)d_in[13];
    const int*   dst_gc   = (const int*)d_in[14];
    const int*   src_gg   = (const int*)d_in[15];
    const int*   dst_gg   = (const int*)d_in[16];

    const int e_cg = in_sizes[11];
    const int e_gc = in_sizes[13];
    const int e_gg = in_sizes[15];

    float* c_out = (float*)d_out;                   // [NC, D]
    float* g_out = (float*)d_out + (size_t)NC * D;  // [NG, D]

    const int nt_cg = (e_cg + TILE - 1) / TILE;
    const int nt_gc = (e_gc + TILE - 1) / TILE;

    // ---- workspace layout (int units) ----
    int* ws = (int*)d_ws;
    size_t p = 0;
    int* cur_cg  = ws + p; p += NB_CG;       // memset region start
    int* cur_gc  = ws + p; p += NB_GC;
    int* cnt_gg  = ws + p; p += NG;
    int* ovf_cnt = ws + p; p += 1;           // memset region end
    const size_t zcount = p;
    float* w_cell = (float*)(ws + p); p += NC;
    float* w_rev  = (float*)(ws + p); p += NG;
    float* w_gg   = (float*)(ws + p); p += NG;
    unsigned* bkt_cg = (unsigned*)(ws + p); p += (size_t)NB_CG * CAP;
    unsigned* bkt_gc = (unsigned*)(ws + p); p += (size_t)NB_GC * CAP;
    int* bkt_gg = ws + p; p += (size_t)NG * GG_CAP;
    p = (p + 1) & ~(size_t)1;                // 8B align for uint2
    uint2* ovf = (uint2*)(ws + p); p += (size_t)OVF_CAP * 2;
    const size_t need_base = p * sizeof(int);
    p = (p + 3) & ~(size_t)3;                // 16B align for uint4 reads
    unsigned short* wc16  = (unsigned short*)(ws + p); p += (size_t)(NC + 1) * D / 2;
    unsigned short* wg16  = (unsigned short*)(ws + p); p += (size_t)(NG + 1) * D / 2;
    unsigned short* wgg16 = (unsigned short*)(ws + p); p += (size_t)(NG + 1) * D / 2;
    const size_t need_full = p * sizeof(int);

    // fallback if workspace too small or sizes pathological for fixed-cap bins
    if (need_base > ws_size || e_cg > 3200000 || e_gc > 3200000 || e_gg > 200000) {
        hipMemsetAsync(d_out, 0, (size_t)out_size * sizeof(float), stream);
        edge_scatter_kernel<<<(e_cg + 15) / 16, 256, 0, stream>>>(
            c_feat, cj_cell, mask_exp, ci_gene, src_cg, dst_cg, g_out, e_cg, 0.5f);
        edge_scatter_kernel<<<(e_gc + 15) / 16, 256, 0, stream>>>(
            g_feat, cj_gene, mask_rev, ci_cell, src_gc, dst_gc, c_out, e_gc, 1.0f);
        edge_scatter_kernel<<<(e_gg + 15) / 16, 256, 0, stream>>>(
            g_feat, cjj_gene, mask_gg, cii_gene, src_gg, dst_gg, g_out, e_gg, 0.5f);
        return;
    }
    const int use_bf16 = (need_full <= ws_size) ? 1 : 0;

    hipMemsetAsync(ws, 0, zcount * sizeof(int), stream);

    partition_kernel<<<nt_cg + nt_gc + 64 + NPREP, 256, 0, stream>>>(
        src_cg, dst_cg, e_cg, nt_cg,
        src_gc, dst_gc, e_gc, nt_gc,
        src_gg, dst_gg, e_gg,
        cur_cg, cur_gc, cnt_gg,
        bkt_cg, bkt_gc, bkt_gg,
        ovf_cnt, ovf,
        cj_cell, mask_exp, cj_gene, mask_rev, cjj_gene, mask_gg,
        w_cell, w_rev, w_gg, c_feat, g_feat, wc16, wg16, wgg16, use_bf16);

    if (use_bf16) {
        gather3_kernel<true><<<NB_CG + NB_GC, 256, 0, stream>>>(
            bkt_cg, cur_cg, bkt_gc, cur_gc,
            (const void*)wc16, (const void*)wg16, (const void*)wgg16,
            c_feat, g_feat,
            w_cell, w_rev, w_gg, ci_gene, cii_gene, ci_cell,
            cnt_gg, bkt_gg, ovf_cnt, ovf, g_out, c_out);
    } else {
        gather3_kernel<false><<<NB_CG + NB_GC, 256, 0, stream>>>(
            bkt_cg, cur_cg, bkt_gc, cur_gc,
            (const void*)c_feat, (const void*)g_feat, (const void*)g_feat,
            c_feat, g_feat,
            w_cell, w_rev, w_gg, ci_gene, cii_gene, ci_cell,
            cnt_gg, bkt_gg, ovf_cnt, ovf, g_out, c_out);
    }
}

// Round 7
// 243.258 us; speedup vs baseline: 1.1053x; 1.0310x over previous
//
#include <hip/hip_runtime.h>

#define NC 50000
#define NG 3000
#define D  64

#define NB_CG 750    // gene bins of 4  (shift 2)
#define NB_GC 782    // cell bins of 64 (shift 6), 782*64 = 50048
#define PBITS 18
#define TILE  4096
#define KTILE (TILE / 256)
#define NPREP 128
#define CAP   4608   // fixed per-bin capacity (mean ~4000, +9.6 sigma for uniform dst)
#define KCAP  ((CAP + 255) / 256)
#define GG_CAP 128   // per-gene gg capacity (mean ~33)
#define OVF_CAP 262144

__device__ inline unsigned short f2bf(float x) {
    unsigned u = __float_as_uint(x);
    unsigned r = u + 0x7FFFu + ((u >> 16) & 1u);
    return (unsigned short)(r >> 16);
}

// unpack a uint4 of 8 bf16 and accumulate (features are pre-weighted)
__device__ __forceinline__ void acc8(const uint4& q, float f[8]) {
    f[0] += __uint_as_float(q.x << 16); f[1] += __uint_as_float(q.x & 0xFFFF0000u);
    f[2] += __uint_as_float(q.y << 16); f[3] += __uint_as_float(q.y & 0xFFFF0000u);
    f[4] += __uint_as_float(q.z << 16); f[5] += __uint_as_float(q.z & 0xFFFF0000u);
    f[6] += __uint_as_float(q.w << 16); f[7] += __uint_as_float(q.w & 0xFFFF0000u);
}

// fp32 fallback row loader: lane l8 holds 8 elements of row s.
__device__ inline void row8f(const float* feat, int s, int l8, float f[8]) {
    const float4* row = (const float4*)(feat + (size_t)s * D);
    const float4 a = row[l8];
    const float4 b = row[l8 + 8];
    f[0] = a.x; f[1] = a.y; f[2] = a.z; f[3] = a.w;
    f[4] = b.x; f[5] = b.y; f[6] = b.z; f[7] = b.w;
}

// ======================= single-pass partition: tiles -> fixed-cap bins =======================
// Edge records cached ONCE in registers across hist/placement. LDS reduced to 2 bin arrays
// (in-place scan; gsadj = global_start - excl so flush is one add) -> 22.7 KB -> 7 blocks/CU.

__global__ __launch_bounds__(256, 7) void partition_kernel(
    const int* __restrict__ src_cg, const int* __restrict__ dst_cg, int e_cg, int nt_cg,
    const int* __restrict__ src_gc, const int* __restrict__ dst_gc, int e_gc, int nt_gc,
    const int* __restrict__ src_gg, const int* __restrict__ dst_gg, int e_gg,
    int* __restrict__ cur_cg, int* __restrict__ cur_gc, int* __restrict__ cnt_gg,
    unsigned* __restrict__ bkt_cg, unsigned* __restrict__ bkt_gc, int* __restrict__ bkt_gg,
    int* __restrict__ ovf_cnt, uint2* __restrict__ ovf,
    const float* __restrict__ cj_cell, const float* __restrict__ mask_exp,
    const float* __restrict__ cj_gene, const float* __restrict__ mask_rev,
    const float* __restrict__ cjj_gene, const float* __restrict__ mask_gg,
    float* __restrict__ w_cell, float* __restrict__ w_rev, float* __restrict__ w_gg,
    const float* __restrict__ c_feat, const float* __restrict__ g_feat,
    unsigned short* __restrict__ wc16, unsigned short* __restrict__ wg16,
    unsigned short* __restrict__ wgg16, int do_cvt)
{
    const int tid = threadIdx.x;
    const int NT2 = nt_cg + nt_gc;

    if (blockIdx.x >= NT2 + 64) {              // ---- prep blocks ----
        const int pb = blockIdx.x - NT2 - 64;
        const long long stride = (long long)NPREP * 256;
        for (long long i = (long long)pb * 256 + tid; i < NC; i += stride)
            w_cell[i] = cj_cell[i] * mask_exp[i];
        for (long long i = (long long)pb * 256 + tid; i < NG; i += stride) {
            w_rev[i] = cj_gene[i] * mask_rev[i];
            w_gg[i]  = cjj_gene[i] * mask_gg[i];
        }
        if (do_cvt) {
            const long long total8 = (long long)(NC + NG) * D / 8;
            for (long long t = (long long)pb * 256 + tid; t < total8; t += stride) {
                const long long base = t * 8;
                if (base < (long long)NC * D) {
                    const int s = (int)(base >> 6);
                    const float w = cj_cell[s] * mask_exp[s];
                    const float4 a = ((const float4*)(c_feat + base))[0];
                    const float4 b = ((const float4*)(c_feat + base))[1];
                    unsigned short* dp = wc16 + base;
                    ((ushort4*)dp)[0] = make_ushort4(f2bf(w*a.x), f2bf(w*a.y), f2bf(w*a.z), f2bf(w*a.w));
                    ((ushort4*)dp)[1] = make_ushort4(f2bf(w*b.x), f2bf(w*b.y), f2bf(w*b.z), f2bf(w*b.w));
                } else {
                    const long long gb = base - (long long)NC * D;
                    const int s = (int)(gb >> 6);
                    const float wr = cj_gene[s] * mask_rev[s];
                    const float wg = cjj_gene[s] * mask_gg[s];
                    const float4 a = ((const float4*)(g_feat + gb))[0];
                    const float4 b = ((const float4*)(g_feat + gb))[1];
                    ((ushort4*)(wg16 + gb))[0]  = make_ushort4(f2bf(wr*a.x), f2bf(wr*a.y), f2bf(wr*a.z), f2bf(wr*a.w));
                    ((ushort4*)(wg16 + gb))[1]  = make_ushort4(f2bf(wr*b.x), f2bf(wr*b.y), f2bf(wr*b.z), f2bf(wr*b.w));
                    ((ushort4*)(wgg16 + gb))[0] = make_ushort4(f2bf(wg*a.x), f2bf(wg*a.y), f2bf(wg*a.z), f2bf(wg*a.w));
                    ((ushort4*)(wgg16 + gb))[1] = make_ushort4(f2bf(wg*b.x), f2bf(wg*b.y), f2bf(wg*b.z), f2bf(wg*b.w));
                }
            }
            if (pb == 0) {                     // zero dummy rows (tail lanes read these)
                for (int i = tid; i < D; i += 256) {
                    wc16[(size_t)NC * D + i] = 0;
                    wg16[(size_t)NG * D + i] = 0;
                    wgg16[(size_t)NG * D + i] = 0;
                }
            }
        }
        return;
    }

    if (blockIdx.x >= NT2) {                   // ---- gg direct partition (64 blocks) ----
        for (long long e = (long long)(blockIdx.x - NT2) * 256 + tid; e < e_gg;
             e += (long long)64 * 256) {
            const int dd = dst_gg[e];
            const int ss = src_gg[e];
            if ((unsigned)dd >= (unsigned)NG || (unsigned)ss >= (unsigned)NG) continue;
            const int pos = atomicAdd(&cnt_gg[dd], 1);
            if (pos < GG_CAP) bkt_gg[dd * GG_CAP + pos] = ss;
            else {
                const int op = atomicAdd(ovf_cnt, 1);
                if (op >= 0 && op < OVF_CAP)
                    ovf[op] = make_uint2((2u << 30) | (unsigned)ss, (unsigned)dd);
            }
        }
        return;
    }

    // ---- tiled partition for cg / gc ----
    const int* src; const int* dst; int ne; int* cur; unsigned* bkt;
    int shift, nbins, t; unsigned rel;
    if (blockIdx.x < nt_cg) { src = src_cg; dst = dst_cg; ne = e_cg; cur = cur_cg; bkt = bkt_cg; shift = 2; nbins = NB_CG; t = blockIdx.x;         rel = 0u; }
    else                    { src = src_gc; dst = dst_gc; ne = e_gc; cur = cur_gc; bkt = bkt_gc; shift = 6; nbins = NB_GC; t = blockIdx.x - nt_cg; rel = 1u; }
    const long long tb = (long long)t * TILE;
    if (tb >= ne) return;
    const int n = (int)((ne - tb) < TILE ? (ne - tb) : TILE);

    __shared__ int toff[784];                  // hist -> excl-scan -> placement cursor
    __shared__ int gsadj[784];                 // global_start - excl  (flush: local = gsadj + i)
    __shared__ unsigned staged[TILE];
    const unsigned PMASK = (1u << PBITS) - 1u;
    const unsigned DMASK = (1u << shift) - 1u;

    for (int i = tid; i < nbins; i += 256) toff[i] = 0;

    // phase 1: load edge records ONCE into registers, histogram from regs
    int rd[KTILE], rs[KTILE];
    #pragma unroll
    for (int k = 0; k < KTILE; ++k) {
        const int i = k * 256 + tid;
        rd[k] = (i < n) ? dst[tb + i] : -1;    // -1 -> bin OOB -> skipped everywhere
        rs[k] = (i < n) ? src[tb + i] : 0;
    }
    __syncthreads();
    #pragma unroll
    for (int k = 0; k < KTILE; ++k) {
        const unsigned b = ((unsigned)rd[k]) >> shift;
        if (b < (unsigned)nbins) atomicAdd(&toff[b], 1);
    }
    __syncthreads();
    if (tid < 64) {                            // in-place excl scan + fused reservation
        int carry = 0;
        for (int c = 0; c < nbins; c += 64) {
            int idx = c + tid;
            int v = (idx < nbins) ? toff[idx] : 0;
            int incl = v;
            #pragma unroll
            for (int d = 1; d < 64; d <<= 1) {
                int x = __shfl_up(incl, d);
                if (tid >= d) incl += x;
            }
            if (idx < nbins) {
                const int excl = incl - v + carry;
                toff[idx] = excl;
                gsadj[idx] = (v ? atomicAdd(&cur[idx], v) : 0) - excl;
            }
            carry += __shfl(incl, 63);
        }
    }
    __syncthreads();
    #pragma unroll
    for (int k = 0; k < KTILE; ++k) {          // bin-sorted placement from regs (toff = cursor)
        const unsigned d = (unsigned)rd[k];
        const unsigned b = d >> shift;
        if (b < (unsigned)nbins) {
            const int p = atomicAdd(&toff[b], 1);
            if (p >= 0 && p < TILE)
                staged[p] = (b << PBITS) | ((unsigned)rs[k] << shift) | (d & DMASK);
        }
    }
    __syncthreads();
    for (int i = tid; i < n; i += 256) {       // flush contiguous runs to fixed-cap bins
        const unsigned v = staged[i];
        const unsigned b = v >> PBITS;
        if (b < (unsigned)nbins) {
            const int local = gsadj[b] + i;    // = gs + (i - excl)
            if (local >= 0 && local < CAP) {
                bkt[(size_t)b * CAP + local] = v & PMASK;
            } else {                           // rare overflow -> spill list
                const unsigned s = (v >> shift) & 0xFFFFu;
                const unsigned dd = (b << shift) | (v & DMASK);
                const int op = atomicAdd(ovf_cnt, 1);
                if (op >= 0 && op < OVF_CAP)
                    ovf[op] = make_uint2((rel << 30) | s, dd);
            }
        }
    }
}

// ======================= fused gather (cg + gg fold | gc), fixed-cap bins =======================
// BF16 path: features are PRE-WEIGHTED bf16 rows; tail lanes read a zero dummy row.
// 4 rows in flight per 8-lane group (8-deep thrashed L2 — round-6 FETCH +45%).
// 8 blocks/CU (launch_bounds(256,8)) for latency hiding; LDS 9.7 KB, VGPR < 64.

template <bool BF16>
__global__ __launch_bounds__(256, 8) void gather3_kernel(
    const unsigned* __restrict__ bkt_cg, const int* __restrict__ cur_cg,
    const unsigned* __restrict__ bkt_gc, const int* __restrict__ cur_gc,
    const void* __restrict__ fc, const void* __restrict__ fg, const void* __restrict__ fgg,
    const float* __restrict__ craw, const float* __restrict__ graw,
    const float* __restrict__ w_cell, const float* __restrict__ w_rev, const float* __restrict__ w_gg,
    const float* __restrict__ ci_gene, const float* __restrict__ cii_gene, const float* __restrict__ ci_cell,
    const int* __restrict__ cnt_gg, const int* __restrict__ bkt_gg,
    const int* __restrict__ ovf_cnt, const uint2* __restrict__ ovf,
    float* __restrict__ g_out, float* __restrict__ c_out)
{
    __shared__ unsigned short sorted[CAP];     // source ids only (16-bit)
    __shared__ int lh[64];                     // hist, then placement cursor (ends = hist)
    __shared__ int loff[64];

    const bool is_cg = (blockIdx.x < NB_CG);
    const int bin = is_cg ? blockIdx.x : blockIdx.x - NB_CG;
    int n = (is_cg ? cur_cg : cur_gc)[bin];
    n = n > CAP ? CAP : n;
    const long long base = (long long)bin * CAP;
    const unsigned* bkt = is_cg ? bkt_cg : bkt_gc;
    const void* feat = is_cg ? fc : fg;
    const float* wsrc = is_cg ? w_cell : w_rev;
    const int shift = is_cg ? 2 : 6;
    const int DIVv = is_cg ? 4 : 64;
    const int KPC  = is_cg ? 16 : 1;           // sort keys per output row
    const int DUM  = is_cg ? NC : NG;          // zero dummy row index
    const int tid  = threadIdx.x;
    const int lane = tid & 63;
    const int wid  = tid >> 6;
    const int grp8 = lane >> 3;                // 8 groups of 8 lanes
    const int l8   = lane & 7;

    // ---- 64-key counting sort into LDS; records cached in regs across phases ----
    for (int i = tid; i < 64; i += 256) lh[i] = 0;
    unsigned rv[KCAP];
    #pragma unroll
    for (int k = 0; k < KCAP; ++k) {
        const int i = k * 256 + tid;
        rv[k] = (i < n) ? bkt[base + i] : 0xFFFFFFFFu;   // sentinel (valid v < 2^18)
    }
    __syncthreads();
    #pragma unroll
    for (int k = 0; k < KCAP; ++k) {
        const unsigned v = rv[k];
        if (v != 0xFFFFFFFFu) {
            const int kk = is_cg ? (int)(((v & 3u) << 4) | (((v >> 2) & 0xFFFFu) >> 12))
                                 : (int)(v & 63u);
            atomicAdd(&lh[kk], 1);
        }
    }
    __syncthreads();
    if (tid < 64) {
        int v = lh[tid];
        int incl = v;
        #pragma unroll
        for (int d = 1; d < 64; d <<= 1) {
            int t = __shfl_up(incl, d);
            if (tid >= d) incl += t;
        }
        loff[tid] = incl - v;
        lh[tid] = 0;                           // lh -> per-key placement cursor
    }
    __syncthreads();
    #pragma unroll
    for (int k = 0; k < KCAP; ++k) {
        const unsigned v = rv[k];
        if (v != 0xFFFFFFFFu) {
            const int kk = is_cg ? (int)(((v & 3u) << 4) | (((v >> 2) & 0xFFFFu) >> 12))
                                 : (int)(v & 63u);
            const int p = loff[kk] + atomicAdd(&lh[kk], 1);
            if (p >= 0 && p < CAP) sorted[p] = (unsigned short)((v >> shift) & 0xFFFFu);
        }
    }
    __syncthreads();                           // after this, lh[k] == per-key count again

    int novf = *ovf_cnt;
    novf = novf < 0 ? 0 : (novf > OVF_CAP ? OVF_CAP : novf);

    for (int cell = wid; cell < DIVv; cell += 4) {
        const int r = (bin << shift) + cell;
        if (r >= (is_cg ? NG : NC)) continue;

        float fA[8] = {0.f, 0.f, 0.f, 0.f, 0.f, 0.f, 0.f, 0.f};
        {
            const int k0 = cell * KPC, k1 = k0 + KPC - 1;
            const int lo = loff[k0], hi = loff[k1] + lh[k1];
            if (BF16) {
                const uint4* fp = (const uint4*)feat;
                for (int jj = lo; jj < hi; jj += 32) {   // 4 rows in flight per group
                    const int b0 = jj + grp8;
                    const int s0 = (b0      < hi) ? (int)sorted[b0]      : DUM;
                    const int s1 = (b0 + 8  < hi) ? (int)sorted[b0 + 8]  : DUM;
                    const int s2 = (b0 + 16 < hi) ? (int)sorted[b0 + 16] : DUM;
                    const int s3 = (b0 + 24 < hi) ? (int)sorted[b0 + 24] : DUM;
                    const uint4 q0 = fp[(size_t)s0 * 8 + l8];
                    const uint4 q1 = fp[(size_t)s1 * 8 + l8];
                    const uint4 q2 = fp[(size_t)s2 * 8 + l8];
                    const uint4 q3 = fp[(size_t)s3 * 8 + l8];
                    acc8(q0, fA); acc8(q1, fA); acc8(q2, fA); acc8(q3, fA);
                }
            } else {
                for (int jj = lo; jj < hi; jj += 8) {
                    const int j = jj + grp8;
                    const bool valid = (j < hi);
                    const int s = valid ? (int)sorted[j] : 0;
                    const float w = valid ? wsrc[s] : 0.0f;
                    float f[8]; row8f((const float*)feat, s, l8, f);
                    #pragma unroll
                    for (int q = 0; q < 8; ++q) fA[q] += w * f[q];
                }
            }
        }

        float fB[8] = {0.f, 0.f, 0.f, 0.f, 0.f, 0.f, 0.f, 0.f};
        if (is_cg) {
            int ngg = cnt_gg[r];
            ngg = ngg > GG_CAP ? GG_CAP : ngg;
            const int* bg = bkt_gg + (size_t)r * GG_CAP;
            if (BF16) {
                const uint4* fp = (const uint4*)fgg;
                for (int jj = 0; jj < ngg; jj += 16) {   // 2 rows in flight
                    const int j0 = jj + grp8;
                    const int j1 = jj + 8 + grp8;
                    const int s0 = (j0 < ngg) ? bg[j0] : NG;
                    const int s1 = (j1 < ngg) ? bg[j1] : NG;
                    const uint4 q0 = fp[(size_t)s0 * 8 + l8];
                    const uint4 q1 = fp[(size_t)s1 * 8 + l8];
                    acc8(q0, fB); acc8(q1, fB);
                }
            } else {
                for (int jj = 0; jj < ngg; jj += 8) {
                    const int j = jj + grp8;
                    const bool valid = (j < ngg);
                    const int s = valid ? bg[j] : 0;
                    const float w = valid ? w_gg[s] : 0.0f;
                    float f[8]; row8f(graw, s, l8, f);
                    #pragma unroll
                    for (int q = 0; q < 8; ++q) fB[q] += w * f[q];
                }
            }
        }

        #pragma unroll
        for (int q = 0; q < 8; ++q) {
            #pragma unroll
            for (int off = 8; off < 64; off <<= 1) fA[q] += __shfl_xor(fA[q], off);
        }
        if (is_cg) {
            #pragma unroll
            for (int q = 0; q < 8; ++q) {
                #pragma unroll
                for (int off = 8; off < 64; off <<= 1) fB[q] += __shfl_xor(fB[q], off);
            }
        }

        if (grp8 == 0) {
            float o[8];
            float* outp;
            if (is_cg) {
                const float sa = 0.5f * ci_gene[r];
                const float sb = 0.5f * cii_gene[r];
                outp = g_out + (size_t)r * D;
                #pragma unroll
                for (int q = 0; q < 8; ++q) o[q] = sa * fA[q] + sb * fB[q];
            } else {
                const float sc = ci_cell[r];
                outp = c_out + (size_t)r * D;
                #pragma unroll
                for (int q = 0; q < 8; ++q) o[q] = sc * fA[q];
            }

            if (novf > 0) {                    // fold rare overflow edges for this row
                for (int e = 0; e < novf; ++e) {
                    const uint2 vv = ovf[e];
                    const int d = (int)vv.y;
                    if (d != r) continue;
                    const unsigned relv = vv.x >> 30;
                    const int s = (int)(vv.x & 0x3FFFFFFFu);
                    const float* fr = nullptr; float w = 0.f;
                    if (is_cg) {
                        if (relv == 0u && s < NC)      { fr = craw + (size_t)s * D; w = 0.5f * ci_gene[r] * w_cell[s]; }
                        else if (relv == 2u && s < NG) { fr = graw + (size_t)s * D; w = 0.5f * cii_gene[r] * w_gg[s]; }
                    } else {
                        if (relv == 1u && s < NG)      { fr = graw + (size_t)s * D; w = ci_cell[r] * w_rev[s]; }
                    }
                    if (fr) {
                        #pragma unroll
                        for (int q = 0; q < 8; ++q) {
                            const int elem = BF16 ? (8 * l8 + q)
                                                  : (q < 4 ? 4 * l8 + q : 32 + 4 * l8 + (q - 4));
                            o[q] += w * fr[elem];
                        }
                    }
                }
            }

            if (BF16) {
                *(float4*)(outp + 8 * l8)     = make_float4(o[0], o[1], o[2], o[3]);
                *(float4*)(outp + 8 * l8 + 4) = make_float4(o[4], o[5], o[6], o[7]);
            } else {
                *(float4*)(outp + 4 * l8)      = make_float4(o[0], o[1], o[2], o[3]);
                *(float4*)(outp + 32 + 4 * l8) = make_float4(o[4], o[5], o[6], o[7]);
            }
        }
    }
}

// ======================= fallback (atomic scatter) =======================

__global__ __launch_bounds__(256) void edge_scatter_kernel(
    const float* __restrict__ feat, const float* __restrict__ cj,
    const float* __restrict__ mask, const float* __restrict__ ci,
    const int* __restrict__ src, const int* __restrict__ dst,
    float* __restrict__ out, int nedges, float alpha)
{
    const int lane16 = threadIdx.x & 15;
    const int eloc   = threadIdx.x >> 4;
    const long long e = (long long)blockIdx.x * 16 + eloc;
    if (e >= nedges) return;
    const int s = src[e];
    const int t = dst[e];
    const float w = cj[s] * mask[s] * ci[t] * alpha;
    const float4 v = *(const float4*)(feat + (size_t)s * D + lane16 * 4);
    float* o = out + (size_t)t * D + lane16 * 4;
#if defined(__HIP_DEVICE_COMPILE__)
    unsafeAtomicAdd(o + 0, w * v.x);
    unsafeAtomicAdd(o + 1, w * v.y);
    unsafeAtomicAdd(o + 2, w * v.z);
    unsafeAtomicAdd(o + 3, w * v.w);
#endif
}

// ======================= launch =======================

extern "C" void kernel_launch(void* const* d_in, const int* in_sizes, int n_in,
                              void* d_out, int out_size, void* d_ws, size_t ws_size,
                              hipStream_t stream)
{
    const float* c_feat   = (const float*)d_in[0];
    const float* g_feat   = (const float*)d_in[1];
    const float* cj_cell  = (const float*)d_in[2];
    const float* ci_cell  = (const float*)d_in[3];
    const float* cj_gene  = (const float*)d_in[4];
    const float* ci_gene  = (const float*)d_in[5];
    const float* cjj_gene = (const float*)d_in[6];
    const float* cii_gene = (const float*)d_in[7];
    const float* mask_exp = (const float*)d_in[8];
    const float* mask_rev = (const float*)d_in[9];
    const float* mask_gg  = (const float*)d_in[10];
    const int*   src_cg   = (const int*)d_in[11];
    const int*   dst_cg   = (const int*)d_in[12];
    const int*   src_gc   = (const int*)d_in[13];
    const int*   dst_gc   = (const int*)d_in[14];
    const int*   src_gg   = (const int*)d_in[15];
    const int*   dst_gg   = (const int*)d_in[16];

    const int e_cg = in_sizes[11];
    const int e_gc = in_sizes[13];
    const int e_gg = in_sizes[15];

    float* c_out = (float*)d_out;                   // [NC, D]
    float* g_out = (float*)d_out + (size_t)NC * D;  // [NG, D]

    const int nt_cg = (e_cg + TILE - 1) / TILE;
    const int nt_gc = (e_gc + TILE - 1) / TILE;

    // ---- workspace layout (int units) ----
    int* ws = (int*)d_ws;
    size_t p = 0;
    int* cur_cg  = ws + p; p += NB_CG;       // memset region start
    int* cur_gc  = ws + p; p += NB_GC;
    int* cnt_gg  = ws + p; p += NG;
    int* ovf_cnt = ws + p; p += 1;           // memset region end
    const size_t zcount = p;
    float* w_cell = (float*)(ws + p); p += NC;
    float* w_rev  = (float*)(ws + p); p += NG;
    float* w_gg   = (float*)(ws + p); p += NG;
    unsigned* bkt_cg = (unsigned*)(ws + p); p += (size_t)NB_CG * CAP;
    unsigned* bkt_gc = (unsigned*)(ws + p); p += (size_t)NB_GC * CAP;
    int* bkt_gg = ws + p; p += (size_t)NG * GG_CAP;
    p = (p + 1) & ~(size_t)1;                // 8B align for uint2
    uint2* ovf = (uint2*)(ws + p); p += (size_t)OVF_CAP * 2;
    const size_t need_base = p * sizeof(int);
    p = (p + 3) & ~(size_t)3;                // 16B align for uint4 reads
    unsigned short* wc16  = (unsigned short*)(ws + p); p += (size_t)(NC + 1) * D / 2;
    unsigned short* wg16  = (unsigned short*)(ws + p); p += (size_t)(NG + 1) * D / 2;
    unsigned short* wgg16 = (unsigned short*)(ws + p); p += (size_t)(NG + 1) * D / 2;
    const size_t need_full = p * sizeof(int);

    // fallback if workspace too small or sizes pathological for fixed-cap bins
    if (need_base > ws_size || e_cg > 3200000 || e_gc > 3200000 || e_gg > 200000) {
        hipMemsetAsync(d_out, 0, (size_t)out_size * sizeof(float), stream);
        edge_scatter_kernel<<<(e_cg + 15) / 16, 256, 0, stream>>>(
            c_feat, cj_cell, mask_exp, ci_gene, src_cg, dst_cg, g_out, e_cg, 0.5f);
        edge_scatter_kernel<<<(e_gc + 15) / 16, 256, 0, stream>>>(
            g_feat, cj_gene, mask_rev, ci_cell, src_gc, dst_gc, c_out, e_gc, 1.0f);
        edge_scatter_kernel<<<(e_gg + 15) / 16, 256, 0, stream>>>(
            g_feat, cjj_gene, mask_gg, cii_gene, src_gg, dst_gg, g_out, e_gg, 0.5f);
        return;
    }
    const int use_bf16 = (need_full <= ws_size) ? 1 : 0;

    hipMemsetAsync(ws, 0, zcount * sizeof(int), stream);

    partition_kernel<<<nt_cg + nt_gc + 64 + NPREP, 256, 0, stream>>>(
        src_cg, dst_cg, e_cg, nt_cg,
        src_gc, dst_gc, e_gc, nt_gc,
        src_gg, dst_gg, e_gg,
        cur_cg, cur_gc, cnt_gg,
        bkt_cg, bkt_gc, bkt_gg,
        ovf_cnt, ovf,
        cj_cell, mask_exp, cj_gene, mask_rev, cjj_gene, mask_gg,
        w_cell, w_rev, w_gg, c_feat, g_feat, wc16, wg16, wgg16, use_bf16);

    if (use_bf16) {
        gather3_kernel<true><<<NB_CG + NB_GC, 256, 0, stream>>>(
            bkt_cg, cur_cg, bkt_gc, cur_gc,
            (const void*)wc16, (const void*)wg16, (const void*)wgg16,
            c_feat, g_feat,
            w_cell, w_rev, w_gg, ci_gene, cii_gene, ci_cell,
            cnt_gg, bkt_gg, ovf_cnt, ovf, g_out, c_out);
    } else {
        gather3_kernel<false><<<NB_CG + NB_GC, 256, 0, stream>>>(
            bkt_cg, cur_cg, bkt_gc, cur_gc,
            (const void*)c_feat, (const void*)g_feat, (const void*)g_feat,
            c_feat, g_feat,
            w_cell, w_rev, w_gg, ci_gene, cii_gene, ci_cell,
            cnt_gg, bkt_gg, ovf_cnt, ovf, g_out, c_out);
    }
}